// Round 7
// baseline (659.448 us; speedup 1.0000x reference)
//
#include <hip/hip_runtime.h>
#include <hip/hip_bf16.h>
#include <math.h>

// ---------------------------------------------------------------------------
// CustomTransformerEncoderLayer (linear attention, ELU+1 feature map)
// S=2048 B=8 D=1024 F=4096, fp32 in/out, bf16 MFMA internals.
//
// Round 7: barrier-collapse. R3/R5/R6 all sat at MfmaUtil ~41% regardless of
// vmcnt placement -> the 16 barriers/iteration were the cost (8 waves,
// 1 block/CU: every barrier pays max wave skew). New K-loop: 2 barriers per
// K-tile, double-buffered, counted vmcnt(8) that waits on loads issued a full
// tile earlier (zero expected stall). Reads+MFMAs of a tile run barrier-free
// (compiler/lgkmcnt schedule them; 2 waves/SIMD overlap). Layout/swizzle/
// staging geometry identical to the passing R6 kernel.
// ---------------------------------------------------------------------------

typedef __attribute__((ext_vector_type(8))) short short8;
typedef __attribute__((ext_vector_type(4))) short short4_t;
typedef __attribute__((ext_vector_type(4))) float f32x4;

#define S_DIM 2048
#define B_DIM 8
#define D_DIM 1024
#define F_DIM 4096

__device__ __forceinline__ unsigned short f2bf(float f) {
  __hip_bfloat16 h = __float2bfloat16(f);
  return *reinterpret_cast<unsigned short*>(&h);
}

#define GLD16(gp, sp)                                              \
  __builtin_amdgcn_global_load_lds(                                \
      (const __attribute__((address_space(1))) void*)(gp),         \
      (__attribute__((address_space(3))) void*)(sp), 16, 0, 0)

#define BAR()                                  \
  do {                                         \
    asm volatile("" ::: "memory");             \
    __builtin_amdgcn_s_barrier();              \
    asm volatile("" ::: "memory");             \
  } while (0)
#define WAITVM8() asm volatile("s_waitcnt vmcnt(8)" ::: "memory")
#define WAITVM0() asm volatile("s_waitcnt vmcnt(0)" ::: "memory")

// ---------------------------------------------------------------------------
// gemm256: C[i,j] = sum_k A[i,k]*B[j,k], BM=BN=256, BK=64, 512 thr (8 waves
// 2Mx4N), per-wave 128x64 output. Double-buffered 128KiB LDS, 2 barriers per
// K-tile, counted vmcnt(8), chunk^row XOR swizzle (0 bank conflicts).
// Requires M%256==0, N%256==0, K%128==0, gridDim.x*gridDim.y%8==0.
// LDS map: buf b at b*65536 B; A_h at h*16384, B_nh at 32768+nh*16384.
// Region slot(row r, chunk c') holds global chunk c = c' ^ (r&7) (16B chunks).
// Steady tile t (buf = t&1):
//   { reads quadrant-by-quadrant + 16x4 MFMA, no internal barriers }
//   BAR(); if (t+2<T) { STAGE tile t+2 -> buf; vmcnt(8) /* lands t+1 */ }
//   else vmcnt(0); BAR();
// EPI: 3 relu+bias->bf16, 4 bias+f32residual->f32, 5 bias+(col<2048?elu)->bf16
// ---------------------------------------------------------------------------
template <int EPI>
__global__ __launch_bounds__(512, 2) void gemm256_kernel(
    const unsigned short* __restrict__ A, long lda, long sA,
    const unsigned short* __restrict__ B, long ldb, long sB,
    void* __restrict__ Cv, long ldc, long sC,
    const float* __restrict__ bias,
    const float* __restrict__ resid, long ldr, long sR, int K) {
  __shared__ short lds[65536];  // 128 KiB
  // T1 XCD swizzle
  const int gx = gridDim.x;
  const int nwg = gx * gridDim.y;
  const int orig = blockIdx.y * gx + blockIdx.x;
  const int cpx = nwg >> 3;
  const int wgid = (orig & 7) * cpx + (orig >> 3);
  const int bx = wgid % gx, by = wgid / gx;
  const int bz = blockIdx.z;
  const unsigned short* Ablk = A + (long)bz * sA + (long)by * 256 * lda;
  const unsigned short* Bblk = B + (long)bz * sB + (long)bx * 256 * ldb;

  const int tid = threadIdx.x;
  const int w = tid >> 6, lane = tid & 63;
  const int wm = w >> 2, wn = w & 3;
  const int lr = lane & 15, kh = lane >> 4;

  // staging geometry (2 global_load_lds per thread per quarter-region)
  const int sr = w * 8 + (lane >> 3);              // l=0 local row (0..63)
  const int sc = ((lane & 7) ^ (lane >> 3)) * 8;   // inverse-swizzled src col
  const long aoff0 = (long)sr * lda + sc;
  const long aoff1 = (long)(128 + sr) * lda + sc;
  const int br0 = sr + ((sr >> 5) << 5);
  const int br1 = (64 + sr) + (((64 + sr) >> 5) << 5);
  const long boff0 = (long)br0 * ldb + sc;
  const long boff1 = (long)br1 * ldb + sc;
  const int dst0 = w * 1024;
  const int dst1 = (8 + w) * 1024;

#define STAGE_A(bufOff, h, kt)                                                \
  do {                                                                        \
    const unsigned short* _g = Ablk + (long)(h) * 64 * lda + (long)(kt) * 64; \
    GLD16(_g + aoff0, (char*)lds + (bufOff) + (h)*16384 + dst0);              \
    GLD16(_g + aoff1, (char*)lds + (bufOff) + (h)*16384 + dst1);              \
  } while (0)
#define STAGE_B(bufOff, nh, kt)                                               \
  do {                                                                        \
    const unsigned short* _g = Bblk + (long)(nh) * 32 * ldb + (long)(kt) * 64;\
    GLD16(_g + boff0, (char*)lds + (bufOff) + 32768 + (nh)*16384 + dst0);     \
    GLD16(_g + boff1, (char*)lds + (bufOff) + 32768 + (nh)*16384 + dst1);     \
  } while (0)

  // fragment-read geometry
  const int chk0 = ((kh ^ (lr & 7)) << 4);
  const int chk1 = (((4 + kh) ^ (lr & 7)) << 4);
  const int aRdBase = (wm * 64 + lr) * 128;
  const int bRdBase = (wn * 32 + lr) * 128;

  short8 af[4][2], b0r[2][2], b1r[2][2];
  f32x4 acc[8][4];
#pragma unroll
  for (int m = 0; m < 8; ++m)
#pragma unroll
    for (int n = 0; n < 4; ++n)
#pragma unroll
      for (int j = 0; j < 4; ++j) acc[m][n][j] = 0.f;

#define LDA_H(bufOff, h)                                                     \
  do {                                                                       \
    const char* _p = (const char*)lds + (bufOff) + (h)*16384 + aRdBase;      \
    _Pragma("unroll") for (int m = 0; m < 4; ++m) {                          \
      af[m][0] = *(const short8*)(_p + m * 2048 + chk0);                     \
      af[m][1] = *(const short8*)(_p + m * 2048 + chk1);                     \
    }                                                                        \
  } while (0)
#define LDB_H(dst, bufOff, nh)                                               \
  do {                                                                       \
    const char* _p = (const char*)lds + (bufOff) + 32768 + (nh)*16384 + bRdBase; \
    _Pragma("unroll") for (int n = 0; n < 2; ++n) {                          \
      dst[n][0] = *(const short8*)(_p + n * 2048 + chk0);                    \
      dst[n][1] = *(const short8*)(_p + n * 2048 + chk1);                    \
    }                                                                        \
  } while (0)
#define MFMA_Q(mh, nh, bset)                                                 \
  do {                                                                       \
    _Pragma("unroll") for (int m = 0; m < 4; ++m)                            \
    _Pragma("unroll") for (int n = 0; n < 2; ++n)                            \
    _Pragma("unroll") for (int ks = 0; ks < 2; ++ks)                         \
      acc[(mh)*4 + m][(nh)*2 + n] = __builtin_amdgcn_mfma_f32_16x16x32_bf16( \
          af[m][ks], bset[n][ks], acc[(mh)*4 + m][(nh)*2 + n], 0, 0, 0);     \
  } while (0)

  const int T = K >> 6;
  // prologue: tile0 -> buf0 (8 loads), tile1 -> buf1 (8 loads)
  STAGE_A(0, 0, 0); STAGE_B(0, 0, 0); STAGE_B(0, 1, 0); STAGE_A(0, 1, 0);
  STAGE_A(65536, 0, 1); STAGE_B(65536, 0, 1); STAGE_B(65536, 1, 1);
  STAGE_A(65536, 1, 1);
  WAITVM8();  // 16 outstanding -> wait to 8: tile0 fully landed
  BAR();

  for (int t = 0; t < T; ++t) {
    const int bo = (t & 1) ? 65536 : 0;
    // ---- compute tile t (no internal barriers) ----
    LDA_H(bo, 0); LDB_H(b0r, bo, 0);
    MFMA_Q(0, 0, b0r);
    LDB_H(b1r, bo, 1);
    MFMA_Q(0, 1, b1r);
    LDA_H(bo, 1);
    MFMA_Q(1, 1, b1r);
    MFMA_Q(1, 0, b0r);
    BAR();  // all waves done reading buf bo
    // ---- stage tile t+2 into bo; land tile t+1 ----
    if (t + 2 < T) {
      STAGE_A(bo, 0, t + 2); STAGE_B(bo, 0, t + 2);
      STAGE_B(bo, 1, t + 2); STAGE_A(bo, 1, t + 2);
      WAITVM8();  // 16 outstanding -> 8: tile t+1 landed, t+2 in flight
    } else {
      WAITVM0();  // tail: land tile t+1 (t=T-2) / free (t=T-1)
    }
    BAR();
  }

  // C/D layout: col = lane&15, row = kh*4 + j
  const long gm0 = (long)by * 256 + wm * 128;
  const long gn0 = (long)bx * 256 + wn * 64;
  if constexpr (EPI == 4) {
    float* C = (float*)Cv + (long)bz * sC;
    const float* R = resid + (long)bz * sR;
#pragma unroll
    for (int mg = 0; mg < 8; ++mg)
#pragma unroll
      for (int ng = 0; ng < 4; ++ng) {
        const long col = gn0 + ng * 16 + lr;
        const float bcol = bias[col];
#pragma unroll
        for (int j = 0; j < 4; ++j) {
          const long row = gm0 + mg * 16 + kh * 4 + j;
          C[row * ldc + col] = acc[mg][ng][j] + bcol + R[row * ldr + col];
        }
      }
  } else {
    unsigned short* C = (unsigned short*)Cv + (long)bz * sC;
    const bool do_elu = (EPI == 5) && (gn0 < 2048);  // wave-uniform segment
#pragma unroll
    for (int mg = 0; mg < 8; ++mg)
#pragma unroll
      for (int ng = 0; ng < 4; ++ng) {
        const long col = gn0 + ng * 16 + lr;
        const float bcol = bias[col];
#pragma unroll
        for (int j = 0; j < 4; ++j) {
          const long row = gm0 + mg * 16 + kh * 4 + j;
          float v = acc[mg][ng][j] + bcol;
          if constexpr (EPI == 3) v = fmaxf(v, 0.f);  // relu
          if constexpr (EPI == 5) {
            if (do_elu) v = (v > 0.f) ? (v + 1.f) : expf(v);  // elu+1
          }
          C[row * ldc + col] = f2bf(v);
        }
      }
  }
#undef STAGE_A
#undef STAGE_B
#undef LDA_H
#undef LDB_H
#undef MFMA_Q
}

// ---------------------------------------------------------------------------
// gemm_bt (128^2, 2-phase): kept for KV / Mt (grids too small for 256^2).
// ---------------------------------------------------------------------------
template <int EPI>
__global__ __launch_bounds__(256, 2) void gemm_bt_kernel(
    const unsigned short* __restrict__ A, long lda, long sA,
    const unsigned short* __restrict__ B, long ldb, long sB,
    void* __restrict__ Cv, long ldc, long sC,
    const float* __restrict__ bias,
    const float* __restrict__ resid, long ldr, long sR, int K) {
  __shared__ short As[128 * 32];
  __shared__ short Bs[128 * 32];
  const int gx = gridDim.x;
  const int nwg = gx * gridDim.y;
  const int orig = blockIdx.y * gx + blockIdx.x;
  const int cpx = nwg >> 3;
  const int wgid = (orig & 7) * cpx + (orig >> 3);
  const int bx = wgid % gx;
  const int by = wgid / gx;

  const int bz = blockIdx.z;
  const unsigned short* Ab = A + (long)bz * sA + (long)by * 128 * lda;
  const unsigned short* Bb = B + (long)bz * sB + (long)bx * 128 * ldb;
  const int tid = threadIdx.x;
  const int w = tid >> 6, lane = tid & 63;
  const int srow = lane >> 2;
  const int scol = (lane & 3) * 8;
  const int wr = (w >> 1) * 64, wc = (w & 1) * 64;
  const int lr = lane & 15, kh = lane >> 4;

  f32x4 acc[4][4];
#pragma unroll
  for (int m = 0; m < 4; ++m)
#pragma unroll
    for (int n = 0; n < 4; ++n)
#pragma unroll
      for (int j = 0; j < 4; ++j) acc[m][n][j] = 0.f;

  const unsigned short* ga0 = Ab + (long)(w * 16 + srow) * lda + scol;
  const unsigned short* ga1 = Ab + (long)(64 + w * 16 + srow) * lda + scol;
  const unsigned short* gb0 = Bb + (long)(w * 16 + srow) * ldb + scol;
  const unsigned short* gb1 = Bb + (long)(64 + w * 16 + srow) * ldb + scol;
  short* la0 = &As[(w * 16) * 32];
  short* la1 = &As[(64 + w * 16) * 32];
  short* lb0 = &Bs[(w * 16) * 32];
  short* lb1 = &Bs[(64 + w * 16) * 32];

  for (int k0 = 0; k0 < K; k0 += 32) {
    GLD16(ga0 + k0, la0);
    GLD16(ga1 + k0, la1);
    GLD16(gb0 + k0, lb0);
    GLD16(gb1 + k0, lb1);
    __syncthreads();
    short8 af[4], bf[4];
#pragma unroll
    for (int m = 0; m < 4; ++m)
      af[m] = *(const short8*)&As[(wr + m * 16 + lr) * 32 + kh * 8];
#pragma unroll
    for (int n = 0; n < 4; ++n)
      bf[n] = *(const short8*)&Bs[(wc + n * 16 + lr) * 32 + kh * 8];
#pragma unroll
    for (int m = 0; m < 4; ++m)
#pragma unroll
      for (int n = 0; n < 4; ++n)
        acc[m][n] =
            __builtin_amdgcn_mfma_f32_16x16x32_bf16(af[m], bf[n], acc[m][n], 0, 0, 0);
    __syncthreads();
  }

  const long gm0 = (long)by * 128 + wr;
  const long gn0 = (long)bx * 128 + wc;
  unsigned short* C = (unsigned short*)Cv + (long)bz * sC;
#pragma unroll
  for (int m = 0; m < 4; ++m)
#pragma unroll
    for (int n = 0; n < 4; ++n) {
      const long col = gn0 + n * 16 + lr;
#pragma unroll
      for (int j = 0; j < 4; ++j) {
        const long row = gm0 + m * 16 + kh * 4 + j;
        C[row * ldc + col] = f2bf(acc[m][n][j]);
      }
    }
}

// ---------------------------------------------------------------------------
// transpose: in rows indexed (s*8+b) with element stride ld -> out [B][D][S].
// grid (S/64, D/64, B), 256 threads, LDS 64x68 tile.
// ---------------------------------------------------------------------------
__global__ __launch_bounds__(256) void transpose_kernel(
    const unsigned short* __restrict__ in, unsigned short* __restrict__ out,
    long ld) {
  __shared__ unsigned short t[64][68];
  const int b = blockIdx.z;
  const long s0 = (long)blockIdx.x * 64, d0 = (long)blockIdx.y * 64;
  const int tid = threadIdx.x;
  {
    const int r = tid >> 3, c = (tid & 7) * 8;
#pragma unroll
    for (int it = 0; it < 2; ++it) {
      const int s = r + it * 32;
      const unsigned short* g = &in[((s0 + s) * B_DIM + b) * ld + d0 + c];
      short4_t v0 = *(const short4_t*)g;
      short4_t v1 = *(const short4_t*)(g + 4);
      *(short4_t*)&t[s][c] = v0;
      *(short4_t*)&t[s][c + 4] = v1;
    }
  }
  __syncthreads();
  {
    const int d = tid >> 3, c = (tid & 7) * 8;
#pragma unroll
    for (int it = 0; it < 2; ++it) {
      const int dd = d + it * 32;
      short8 v;
#pragma unroll
      for (int j = 0; j < 8; ++j) v[j] = (short)t[c + j][dd];
      *(short8*)&out[(long)b * ((long)D_DIM * S_DIM) + (d0 + dd) * S_DIM + s0 + c] = v;
    }
  }
}

// ---------------------------------------------------------------------------
// layernorm over last dim (1024). Safe in-place (outf may == in).
// ---------------------------------------------------------------------------
template <int WRITE_BF16>
__global__ __launch_bounds__(256) void layernorm_kernel(
    const float* in, float* outf, unsigned short* __restrict__ outb,
    const float* __restrict__ gamma, const float* __restrict__ beta) {
  const long row = blockIdx.x;
  const float* x = in + row * D_DIM;
  const int tid = threadIdx.x;
  const int lane = tid & 63, w = tid >> 6;
  f32x4 v = *(const f32x4*)&x[tid * 4];
  float s = v[0] + v[1] + v[2] + v[3];
  float q = v[0] * v[0] + v[1] * v[1] + v[2] * v[2] + v[3] * v[3];
#pragma unroll
  for (int off = 32; off > 0; off >>= 1) {
    s += __shfl_down(s, off, 64);
    q += __shfl_down(q, off, 64);
  }
  __shared__ float red[8];
  if (lane == 0) { red[w] = s; red[w + 4] = q; }
  __syncthreads();
  s = red[0] + red[1] + red[2] + red[3];
  q = red[4] + red[5] + red[6] + red[7];
  const float mu = s * (1.f / D_DIM);
  const float var = q * (1.f / D_DIM) - mu * mu;
  const float rs = rsqrtf(var + 1e-5f);
  f32x4 g = *(const f32x4*)&gamma[tid * 4];
  f32x4 bb = *(const f32x4*)&beta[tid * 4];
  f32x4 o;
#pragma unroll
  for (int j = 0; j < 4; ++j) o[j] = (v[j] - mu) * rs * g[j] + bb[j];
  *(f32x4*)&outf[row * D_DIM + tid * 4] = o;
  if constexpr (WRITE_BF16) {
    short4_t ob;
#pragma unroll
    for (int j = 0; j < 4; ++j) ob[j] = (short)f2bf(o[j]);
    *(short4_t*)&outb[row * D_DIM + tid * 4] = ob;
  }
}

__global__ __launch_bounds__(256) void cast_kernel(
    const float* __restrict__ in, unsigned short* __restrict__ out, long n) {
  long i = ((long)blockIdx.x * 256 + threadIdx.x) * 8;
  if (i >= n) return;
  f32x4 a = *(const f32x4*)&in[i];
  f32x4 b = *(const f32x4*)&in[i + 4];
  short8 v;
#pragma unroll
  for (int j = 0; j < 4; ++j) v[j] = (short)f2bf(a[j]);
#pragma unroll
  for (int j = 0; j < 4; ++j) v[4 + j] = (short)f2bf(b[j]);
  *(short8*)&out[i] = v;
}

// ---------------------------------------------------------------------------
// Workspace plan (MB offsets; 240 MB peak). Timeline-checked (same as R5/R6):
//   0-8 w1b, 8-16 w2b (persist)
//   16-80  srcb(16-48, dead@QKV) -> Kt(16-48)/Vt(48-80, dead@KV)
//          -> AO fp32 (written@AO, LN1 in-place) = X (lives to FFN2)
//   80-112 KVm(80-96, dead@Mt), Mt(96-112, dead@AO) -> Xb (written@LN1)
//   112-240 wqkvb(112-118)+bqkv(118-119)+wob(119-121) dead@Mt;
//          QKVb(144-240, written@QKV, Q-slice read@AO, dead after)
//          -> H (written@FFN1)
// ---------------------------------------------------------------------------
extern "C" void kernel_launch(void* const* d_in, const int* in_sizes, int n_in,
                              void* d_out, int out_size, void* d_ws, size_t ws_size,
                              hipStream_t stream) {
  const float* src = (const float*)d_in[0];
  const float* wq  = (const float*)d_in[1];
  const float* bq  = (const float*)d_in[2];
  const float* wk  = (const float*)d_in[3];
  const float* bk  = (const float*)d_in[4];
  const float* wv  = (const float*)d_in[5];
  const float* bv  = (const float*)d_in[6];
  const float* wo  = (const float*)d_in[7];
  const float* bo  = (const float*)d_in[8];
  const float* w1  = (const float*)d_in[9];
  const float* b1  = (const float*)d_in[10];
  const float* w2  = (const float*)d_in[11];
  const float* b2  = (const float*)d_in[12];
  const float* g1  = (const float*)d_in[13];
  const float* be1 = (const float*)d_in[14];
  const float* g2  = (const float*)d_in[15];
  const float* be2 = (const float*)d_in[16];

  const long MB = 1024L * 1024L;
  if (ws_size < 248 * MB) return;
  char* ws = (char*)d_ws;
  unsigned short* w1b   = (unsigned short*)(ws + 0 * MB);
  unsigned short* w2b   = (unsigned short*)(ws + 8 * MB);
  unsigned short* srcb  = (unsigned short*)(ws + 16 * MB);
  unsigned short* Kt    = (unsigned short*)(ws + 16 * MB);   // after srcb dead
  unsigned short* Vt    = (unsigned short*)(ws + 48 * MB);
  float*          AO    = (float*)(ws + 16 * MB);            // after Kt/Vt dead
  float*          X     = (float*)(ws + 16 * MB);            // LN1 in-place
  unsigned short* KVm   = (unsigned short*)(ws + 80 * MB);
  unsigned short* Mt    = (unsigned short*)(ws + 96 * MB);
  unsigned short* Xb    = (unsigned short*)(ws + 80 * MB);   // after KVm/Mt dead
  unsigned short* wqkvb = (unsigned short*)(ws + 112 * MB);  // 6 MB
  float*          bqkv  = (float*)(ws + 118 * MB);           // 12 KB
  unsigned short* wob   = (unsigned short*)(ws + 119 * MB);  // 2 MB
  unsigned short* QKVb  = (unsigned short*)(ws + 144 * MB);  // 96 MB
  unsigned short* H     = (unsigned short*)(ws + 112 * MB);  // after QKV dead

  const dim3 blk(256);
  const dim3 blk512(512);
  // casts + packed bias
  cast_kernel<<<dim3(512), blk, 0, stream>>>(wq, wqkvb, 1048576);
  cast_kernel<<<dim3(512), blk, 0, stream>>>(wk, wqkvb + 1048576, 1048576);
  cast_kernel<<<dim3(512), blk, 0, stream>>>(wv, wqkvb + 2097152, 1048576);
  cast_kernel<<<dim3(512), blk, 0, stream>>>(wo, wob, 1048576);
  cast_kernel<<<dim3(2048), blk, 0, stream>>>(w1, w1b, 4194304);
  cast_kernel<<<dim3(2048), blk, 0, stream>>>(w2, w2b, 4194304);
  cast_kernel<<<dim3(8192), blk, 0, stream>>>(src, srcb, 16777216);
  hipMemcpyAsync(bqkv, bq, 4096, hipMemcpyDeviceToDevice, stream);
  hipMemcpyAsync(bqkv + 1024, bk, 4096, hipMemcpyDeviceToDevice, stream);
  hipMemcpyAsync(bqkv + 2048, bv, 4096, hipMemcpyDeviceToDevice, stream);

  // fused QKV: [16384,1024] @ [3072,1024]^T -> QKVb [16384,3072]
  gemm256_kernel<5><<<dim3(12, 64, 1), blk512, 0, stream>>>(
      srcb, 1024, 0, wqkvb, 1024, 0, QKVb, 3072, 0, bqkv, nullptr, 0, 0, 1024);

  // per-batch transposes of K,V slices -> [B][D][S]
  transpose_kernel<<<dim3(32, 16, 8), blk, 0, stream>>>(QKVb + 1024, Kt, 3072);
  transpose_kernel<<<dim3(32, 16, 8), blk, 0, stream>>>(QKVb + 2048, Vt, 3072);

  // KV[d,f] = sum_s Kt[d,s]*Vt[f,s]  (M=N=1024, K=2048, batch 8) -- 128^2
  gemm_bt_kernel<0><<<dim3(8, 8, 8), blk, 0, stream>>>(
      Kt, 2048, 2097152, Vt, 2048, 2097152, KVm, 1024, 1048576,
      nullptr, nullptr, 0, 0, 2048);
  // Mt[e,d] = sum_f wo[e,f]*KV[d,f]  (M=N=1024, K=1024, batch 8) -- 128^2
  gemm_bt_kernel<0><<<dim3(8, 8, 8), blk, 0, stream>>>(
      wob, 1024, 0, KVm, 1024, 1048576, Mt, 1024, 1048576,
      nullptr, nullptr, 0, 0, 1024);
  // AO[s,b,e] = sum_d Q[s,b,d]*Mt[e,d] + bo[e] + src  (Q read from QKVb)
  gemm256_kernel<4><<<dim3(4, 8, 8), blk512, 0, stream>>>(
      QKVb, 24576, 3072, Mt, 1024, 1048576, AO, 8192, 1024,
      bo, src, 8192, 1024, 1024);

  // x = LN(AO) in-place -> X fp32 + Xb bf16
  layernorm_kernel<1><<<dim3(16384), blk, 0, stream>>>(AO, X, Xb, g1, be1);

  // FFN, full M=16384
  gemm256_kernel<3><<<dim3(16, 64, 1), blk512, 0, stream>>>(
      Xb, 1024, 0, w1b, 1024, 0, H, 4096, 0, b1, nullptr, 0, 0, 1024);
  gemm256_kernel<4><<<dim3(4, 64, 1), blk512, 0, stream>>>(
      H, 4096, 0, w2b, 4096, 0, (float*)d_out, 1024, 0,
      b2, X, 1024, 0, 4096);

  // final LN in-place on d_out
  layernorm_kernel<0><<<dim3(16384), blk, 0, stream>>>(
      (float*)d_out, (float*)d_out, nullptr, g2, be2);
}

// Round 9
// 650.606 us; speedup vs baseline: 1.0136x; 1.0136x over previous
//
#include <hip/hip_runtime.h>
#include <hip/hip_bf16.h>
#include <math.h>

// ---------------------------------------------------------------------------
// CustomTransformerEncoderLayer (linear attention, ELU+1 feature map)
// S=2048 B=8 D=1024 F=4096, fp32 in/out, bf16 MFMA internals.
//
// Round 9: R8 peel-bug fix. R8's peeled tail dropped ALL stages, but R6's
// final iteration legitimately staged buf1.A1 <- tile T-1 at ph0; without it
// the peel read stale A1 (tile T-3) -> absmax 1.06. Fix: peel ph0 issues
// STAGE_A(buf1, A1, rel=1) (pA sits at tile T-2 after the loop), and the
// peel's vmcnt(0) moves to peel ph3 (lands all four buf1 quarters before any
// buf1 read). Rest byte-identical to R8: single lgkmcnt(0)+sched_barrier
// fence per phase (rule 18), strength-reduced SGPR addressing, vmcnt(6) at
// ph3/ph7 only, chunk^row XOR swizzle.
// ---------------------------------------------------------------------------

typedef __attribute__((ext_vector_type(8))) short short8;
typedef __attribute__((ext_vector_type(4))) short short4_t;
typedef __attribute__((ext_vector_type(4))) float f32x4;

#define S_DIM 2048
#define B_DIM 8
#define D_DIM 1024
#define F_DIM 4096

__device__ __forceinline__ unsigned short f2bf(float f) {
  __hip_bfloat16 h = __float2bfloat16(f);
  return *reinterpret_cast<unsigned short*>(&h);
}

#define GLD16(gp, sp)                                              \
  __builtin_amdgcn_global_load_lds(                                \
      (const __attribute__((address_space(1))) void*)(gp),         \
      (__attribute__((address_space(3))) void*)(sp), 16, 0, 0)

#define BAR()                                  \
  do {                                         \
    asm volatile("" ::: "memory");             \
    __builtin_amdgcn_s_barrier();              \
    asm volatile("" ::: "memory");             \
  } while (0)
#define WAITVM6() asm volatile("s_waitcnt vmcnt(6)" ::: "memory")
#define WAITVM10() asm volatile("s_waitcnt vmcnt(10)" ::: "memory")
#define WAITVM0() asm volatile("s_waitcnt vmcnt(0)" ::: "memory")
// rule 18: lgkmcnt(0) then sched_barrier(0) so MFMAs can't hoist above it.
#define LGKM0_FENCE()                                        \
  do {                                                       \
    asm volatile("s_waitcnt lgkmcnt(0)" ::: "memory");       \
    __builtin_amdgcn_sched_barrier(0);                       \
  } while (0)

// ---------------------------------------------------------------------------
// gemm256: C[i,j] = sum_k A[i,k]*B[j,k], BM=BN=256, BK=64, 512 thr (8 waves
// 2Mx4N), per-wave 128x64 output. 8-phase K-loop, double-buffered 128KiB LDS,
// chunk^row XOR swizzle (0 bank conflicts), vmcnt(6) at ph3/ph7 only.
// Requires M%256==0, N%256==0, K%128==0, K>=256, gridDim.x*gridDim.y%8==0.
// LDS map: buf b at b*65536 B; A_h at h*16384, B_nh at 32768+nh*16384.
// Region slot(row r, chunk c') holds global chunk c = c' ^ (r&7) (16B chunks).
// Steady iteration i (even tile e=2i in buf0, odd o=2i+1 in buf1):
//  ph0: rd A0e[8]      stage b1.A1(rel1)  BAR lgkm0 MFMA(0,0,b0r) BAR
//  ph1: rd B1e->b1r[4] stage b0.A0(rel2)  BAR lgkm0 MFMA(0,1,b1r) BAR
//  ph2: rd A1e[8]      stage b0.B0(rel2)  BAR lgkm0 MFMA(1,1,b1r) BAR
//  ph3:                stage b0.B1(rel2)  vmcnt6 BAR MFMA(1,0,b0r)
//                                         rd b1.B0->b0r[4] BAR
//  ph4..7: same on buf1, stages rel3, vmcnt6 + b0r <- b0.B0.
// Wait invariant: 6 loads (3 quarter-stages) outstanding after each vmcnt(6);
// every LDS read is behind the wait+barrier pair that lands its region.
// Peel (tiles T-2/T-1): ph0 stages b1.A1(rel1)=T-1.A1; vmcnt(0) at peel ph3.
// EPI: 3 relu+bias->bf16, 4 bias+f32residual->f32, 5 bias+(col<2048?elu)->bf16
// ---------------------------------------------------------------------------
template <int EPI>
__global__ __launch_bounds__(512, 2) void gemm256_kernel(
    const unsigned short* __restrict__ A, long lda, long sA,
    const unsigned short* __restrict__ B, long ldb, long sB,
    void* __restrict__ Cv, long ldc, long sC,
    const float* __restrict__ bias,
    const float* __restrict__ resid, long ldr, long sR, int K) {
  __shared__ short lds[65536];  // 128 KiB
  // T1 XCD swizzle
  const int gx = gridDim.x;
  const int nwg = gx * gridDim.y;
  const int orig = blockIdx.y * gx + blockIdx.x;
  const int cpx = nwg >> 3;
  const int wgid = (orig & 7) * cpx + (orig >> 3);
  const int bx = wgid % gx, by = wgid / gx;
  const int bz = blockIdx.z;
  const unsigned short* Ablk = A + (long)bz * sA + (long)by * 256 * lda;
  const unsigned short* Bblk = B + (long)bz * sB + (long)bx * 256 * ldb;

  const int tid = threadIdx.x;
  const int w = tid >> 6, lane = tid & 63;
  const int wm = w >> 2, wn = w & 3;
  const int lr = lane & 15, kh = lane >> 4;

  // staging geometry (2 global_load_lds per thread per quarter-region)
  const int sr = w * 8 + (lane >> 3);              // l=0 local row (0..63)
  const int sc = ((lane & 7) ^ (lane >> 3)) * 8;   // inverse-swizzled src col
  const int br0 = sr + ((sr >> 5) << 5);
  // base pointers (advanced +128 elems per main-loop iteration)
  const unsigned short* pA = Ablk + (long)sr * lda + sc;   // A h=0, load0
  const unsigned short* pB = Bblk + (long)br0 * ldb + sc;  // B nh=0, load0
  // wave-uniform deltas (SGPR): load1 = +128 rows for both A and B
  const long dA1 = 128 * lda, dAh = 64 * lda;
  const long dB1 = 128 * ldb, dBh = 32 * ldb;
  const int dst0 = w * 1024;
  const int dst1 = (8 + w) * 1024;

#define STAGE_A(bufOff, h, rel)                                               \
  do {                                                                        \
    GLD16(pA + (h) * dAh + (rel) * 64,                                        \
          (char*)lds + (bufOff) + (h)*16384 + dst0);                          \
    GLD16(pA + (h) * dAh + dA1 + (rel) * 64,                                  \
          (char*)lds + (bufOff) + (h)*16384 + dst1);                          \
  } while (0)
#define STAGE_B(bufOff, nh, rel)                                              \
  do {                                                                        \
    GLD16(pB + (nh) * dBh + (rel) * 64,                                       \
          (char*)lds + (bufOff) + 32768 + (nh)*16384 + dst0);                 \
    GLD16(pB + (nh) * dBh + dB1 + (rel) * 64,                                 \
          (char*)lds + (bufOff) + 32768 + (nh)*16384 + dst1);                 \
  } while (0)

  // fragment-read geometry
  const int chk0 = ((kh ^ (lr & 7)) << 4);
  const int chk1 = (((4 + kh) ^ (lr & 7)) << 4);
  const int aRdBase = (wm * 64 + lr) * 128;
  const int bRdBase = (wn * 32 + lr) * 128;

  short8 af[4][2], b0r[2][2], b1r[2][2];
  f32x4 acc[8][4];
#pragma unroll
  for (int m = 0; m < 8; ++m)
#pragma unroll
    for (int n = 0; n < 4; ++n)
#pragma unroll
      for (int j = 0; j < 4; ++j) acc[m][n][j] = 0.f;

#define LDA_H(bufOff, h)                                                     \
  do {                                                                       \
    const char* _p = (const char*)lds + (bufOff) + (h)*16384 + aRdBase;      \
    _Pragma("unroll") for (int m = 0; m < 4; ++m) {                          \
      af[m][0] = *(const short8*)(_p + m * 2048 + chk0);                     \
      af[m][1] = *(const short8*)(_p + m * 2048 + chk1);                     \
    }                                                                        \
  } while (0)
#define LDB_H(dst, bufOff, nh)                                               \
  do {                                                                       \
    const char* _p = (const char*)lds + (bufOff) + 32768 + (nh)*16384 + bRdBase; \
    _Pragma("unroll") for (int n = 0; n < 2; ++n) {                          \
      dst[n][0] = *(const short8*)(_p + n * 2048 + chk0);                    \
      dst[n][1] = *(const short8*)(_p + n * 2048 + chk1);                    \
    }                                                                        \
  } while (0)
#define MFMA_Q(mh, nh, bset)                                                 \
  do {                                                                       \
    __builtin_amdgcn_s_setprio(1);                                           \
    _Pragma("unroll") for (int m = 0; m < 4; ++m)                            \
    _Pragma("unroll") for (int n = 0; n < 2; ++n)                            \
    _Pragma("unroll") for (int ks = 0; ks < 2; ++ks)                         \
      acc[(mh)*4 + m][(nh)*2 + n] = __builtin_amdgcn_mfma_f32_16x16x32_bf16( \
          af[m][ks], bset[n][ks], acc[(mh)*4 + m][(nh)*2 + n], 0, 0, 0);     \
    __builtin_amdgcn_s_setprio(0);                                           \
  } while (0)

  const int T = K >> 6;  // T even, >=4
  // prologue FIFO: t0.{A0,B0,B1,A1} -> buf0, t1.{A0,B0,B1} -> buf1.
  STAGE_A(0, 0, 0); STAGE_B(0, 0, 0); STAGE_B(0, 1, 0); STAGE_A(0, 1, 0);
  STAGE_A(65536, 0, 1); STAGE_B(65536, 0, 1); STAGE_B(65536, 1, 1);
  WAITVM10(); BAR();
  LDB_H(b0r, 0, 0);  // preload even-tile B0

  for (int i = 0; i < (T >> 1) - 1; ++i) {
    // ph0
    LDA_H(0, 0); STAGE_A(65536, 1, 1);
    BAR(); LGKM0_FENCE(); MFMA_Q(0, 0, b0r); BAR();
    // ph1
    LDB_H(b1r, 0, 1); STAGE_A(0, 0, 2);
    BAR(); LGKM0_FENCE(); MFMA_Q(0, 1, b1r); BAR();
    // ph2
    LDA_H(0, 1); STAGE_B(0, 0, 2);
    BAR(); LGKM0_FENCE(); MFMA_Q(1, 1, b1r); BAR();
    // ph3: vmcnt(6) lands the odd tile; post-MFMA read of b1.B0.
    STAGE_B(0, 1, 2);
    WAITVM6(); BAR(); MFMA_Q(1, 0, b0r); LDB_H(b0r, 65536, 0); BAR();
    // ph4
    LDA_H(65536, 0); STAGE_A(0, 1, 2);
    BAR(); LGKM0_FENCE(); MFMA_Q(0, 0, b0r); BAR();
    // ph5
    LDB_H(b1r, 65536, 1); STAGE_A(65536, 0, 3);
    BAR(); LGKM0_FENCE(); MFMA_Q(0, 1, b1r); BAR();
    // ph6
    LDA_H(65536, 1); STAGE_B(65536, 0, 3);
    BAR(); LGKM0_FENCE(); MFMA_Q(1, 1, b1r); BAR();
    // ph7: vmcnt(6) lands the next even tile; read b0.B0(rel2) post-MFMA.
    STAGE_B(65536, 1, 3);
    WAITVM6(); BAR(); MFMA_Q(1, 0, b0r); LDB_H(b0r, 0, 0); BAR();
    pA += 128; pB += 128;  // advance 2 K-tiles
  }

  // ---- peeled last iteration: tiles T-2 (buf0, rel0) and T-1 (buf1, rel1).
  // buf0 fully landed by the final main-loop ph7 vmcnt(6). Stage the one
  // missing quarter (T-1's A1) here; vmcnt(0) at peel ph3 lands all of buf1.
  // ph0
  LDA_H(0, 0); STAGE_A(65536, 1, 1);
  BAR(); LGKM0_FENCE(); MFMA_Q(0, 0, b0r); BAR();
  // ph1
  LDB_H(b1r, 0, 1);
  BAR(); LGKM0_FENCE(); MFMA_Q(0, 1, b1r); BAR();
  // ph2
  LDA_H(0, 1);
  BAR(); LGKM0_FENCE(); MFMA_Q(1, 1, b1r); BAR();
  // ph3: land ALL buf1 quarters (incl. the peel-ph0 stage), then read B0.
  WAITVM0(); BAR(); MFMA_Q(1, 0, b0r); LDB_H(b0r, 65536, 0); BAR();
  // ph4
  LDA_H(65536, 0);
  BAR(); LGKM0_FENCE(); MFMA_Q(0, 0, b0r); BAR();
  // ph5
  LDB_H(b1r, 65536, 1);
  BAR(); LGKM0_FENCE(); MFMA_Q(0, 1, b1r); BAR();
  // ph6
  LDA_H(65536, 1);
  BAR(); LGKM0_FENCE(); MFMA_Q(1, 1, b1r); BAR();
  // ph7
  LGKM0_FENCE(); MFMA_Q(1, 0, b0r);

  // C/D layout: col = lane&15, row = kh*4 + j
  const long gm0 = (long)by * 256 + wm * 128;
  const long gn0 = (long)bx * 256 + wn * 64;
  if constexpr (EPI == 4) {
    float* C = (float*)Cv + (long)bz * sC;
    const float* R = resid + (long)bz * sR;
#pragma unroll
    for (int mg = 0; mg < 8; ++mg)
#pragma unroll
      for (int ng = 0; ng < 4; ++ng) {
        const long col = gn0 + ng * 16 + lr;
        const float bcol = bias[col];
#pragma unroll
        for (int j = 0; j < 4; ++j) {
          const long row = gm0 + mg * 16 + kh * 4 + j;
          C[row * ldc + col] = acc[mg][ng][j] + bcol + R[row * ldr + col];
        }
      }
  } else {
    unsigned short* C = (unsigned short*)Cv + (long)bz * sC;
    const bool do_elu = (EPI == 5) && (gn0 < 2048);  // wave-uniform segment
#pragma unroll
    for (int mg = 0; mg < 8; ++mg)
#pragma unroll
      for (int ng = 0; ng < 4; ++ng) {
        const long col = gn0 + ng * 16 + lr;
        const float bcol = bias[col];
#pragma unroll
        for (int j = 0; j < 4; ++j) {
          const long row = gm0 + mg * 16 + kh * 4 + j;
          float v = acc[mg][ng][j] + bcol;
          if constexpr (EPI == 3) v = fmaxf(v, 0.f);  // relu
          if constexpr (EPI == 5) {
            if (do_elu) v = (v > 0.f) ? (v + 1.f) : expf(v);  // elu+1
          }
          C[row * ldc + col] = f2bf(v);
        }
      }
  }
#undef STAGE_A
#undef STAGE_B
#undef LDA_H
#undef LDB_H
#undef MFMA_Q
}

// ---------------------------------------------------------------------------
// gemm_bt (128^2, 2-phase): kept for KV / Mt (grids too small for 256^2).
// ---------------------------------------------------------------------------
template <int EPI>
__global__ __launch_bounds__(256, 2) void gemm_bt_kernel(
    const unsigned short* __restrict__ A, long lda, long sA,
    const unsigned short* __restrict__ B, long ldb, long sB,
    void* __restrict__ Cv, long ldc, long sC,
    const float* __restrict__ bias,
    const float* __restrict__ resid, long ldr, long sR, int K) {
  __shared__ short As[128 * 32];
  __shared__ short Bs[128 * 32];
  const int gx = gridDim.x;
  const int nwg = gx * gridDim.y;
  const int orig = blockIdx.y * gx + blockIdx.x;
  const int cpx = nwg >> 3;
  const int wgid = (orig & 7) * cpx + (orig >> 3);
  const int bx = wgid % gx;
  const int by = wgid / gx;

  const int bz = blockIdx.z;
  const unsigned short* Ab = A + (long)bz * sA + (long)by * 128 * lda;
  const unsigned short* Bb = B + (long)bz * sB + (long)bx * 128 * ldb;
  const int tid = threadIdx.x;
  const int w = tid >> 6, lane = tid & 63;
  const int srow = lane >> 2;
  const int scol = (lane & 3) * 8;
  const int wr = (w >> 1) * 64, wc = (w & 1) * 64;
  const int lr = lane & 15, kh = lane >> 4;

  f32x4 acc[4][4];
#pragma unroll
  for (int m = 0; m < 4; ++m)
#pragma unroll
    for (int n = 0; n < 4; ++n)
#pragma unroll
      for (int j = 0; j < 4; ++j) acc[m][n][j] = 0.f;

  const unsigned short* ga0 = Ab + (long)(w * 16 + srow) * lda + scol;
  const unsigned short* ga1 = Ab + (long)(64 + w * 16 + srow) * lda + scol;
  const unsigned short* gb0 = Bb + (long)(w * 16 + srow) * ldb + scol;
  const unsigned short* gb1 = Bb + (long)(64 + w * 16 + srow) * ldb + scol;
  short* la0 = &As[(w * 16) * 32];
  short* la1 = &As[(64 + w * 16) * 32];
  short* lb0 = &Bs[(w * 16) * 32];
  short* lb1 = &Bs[(64 + w * 16) * 32];

  for (int k0 = 0; k0 < K; k0 += 32) {
    GLD16(ga0 + k0, la0);
    GLD16(ga1 + k0, la1);
    GLD16(gb0 + k0, lb0);
    GLD16(gb1 + k0, lb1);
    __syncthreads();
    short8 af[4], bf[4];
#pragma unroll
    for (int m = 0; m < 4; ++m)
      af[m] = *(const short8*)&As[(wr + m * 16 + lr) * 32 + kh * 8];
#pragma unroll
    for (int n = 0; n < 4; ++n)
      bf[n] = *(const short8*)&Bs[(wc + n * 16 + lr) * 32 + kh * 8];
#pragma unroll
    for (int m = 0; m < 4; ++m)
#pragma unroll
      for (int n = 0; n < 4; ++n)
        acc[m][n] =
            __builtin_amdgcn_mfma_f32_16x16x32_bf16(af[m], bf[n], acc[m][n], 0, 0, 0);
    __syncthreads();
  }

  const long gm0 = (long)by * 128 + wr;
  const long gn0 = (long)bx * 128 + wc;
  unsigned short* C = (unsigned short*)Cv + (long)bz * sC;
#pragma unroll
  for (int m = 0; m < 4; ++m)
#pragma unroll
    for (int n = 0; n < 4; ++n) {
      const long col = gn0 + n * 16 + lr;
#pragma unroll
      for (int j = 0; j < 4; ++j) {
        const long row = gm0 + m * 16 + kh * 4 + j;
        C[row * ldc + col] = f2bf(acc[m][n][j]);
      }
    }
}

// ---------------------------------------------------------------------------
// transpose: in rows indexed (s*8+b) with element stride ld -> out [B][D][S].
// grid (S/64, D/64, B), 256 threads, LDS 64x68 tile.
// ---------------------------------------------------------------------------
__global__ __launch_bounds__(256) void transpose_kernel(
    const unsigned short* __restrict__ in, unsigned short* __restrict__ out,
    long ld) {
  __shared__ unsigned short t[64][68];
  const int b = blockIdx.z;
  const long s0 = (long)blockIdx.x * 64, d0 = (long)blockIdx.y * 64;
  const int tid = threadIdx.x;
  {
    const int r = tid >> 3, c = (tid & 7) * 8;
#pragma unroll
    for (int it = 0; it < 2; ++it) {
      const int s = r + it * 32;
      const unsigned short* g = &in[((s0 + s) * B_DIM + b) * ld + d0 + c];
      short4_t v0 = *(const short4_t*)g;
      short4_t v1 = *(const short4_t*)(g + 4);
      *(short4_t*)&t[s][c] = v0;
      *(short4_t*)&t[s][c + 4] = v1;
    }
  }
  __syncthreads();
  {
    const int d = tid >> 3, c = (tid & 7) * 8;
#pragma unroll
    for (int it = 0; it < 2; ++it) {
      const int dd = d + it * 32;
      short8 v;
#pragma unroll
      for (int j = 0; j < 8; ++j) v[j] = (short)t[c + j][dd];
      *(short8*)&out[(long)b * ((long)D_DIM * S_DIM) + (d0 + dd) * S_DIM + s0 + c] = v;
    }
  }
}

// ---------------------------------------------------------------------------
// layernorm over last dim (1024). Safe in-place (outf may == in).
// ---------------------------------------------------------------------------
template <int WRITE_BF16>
__global__ __launch_bounds__(256) void layernorm_kernel(
    const float* in, float* outf, unsigned short* __restrict__ outb,
    const float* __restrict__ gamma, const float* __restrict__ beta) {
  const long row = blockIdx.x;
  const float* x = in + row * D_DIM;
  const int tid = threadIdx.x;
  const int lane = tid & 63, w = tid >> 6;
  f32x4 v = *(const f32x4*)&x[tid * 4];
  float s = v[0] + v[1] + v[2] + v[3];
  float q = v[0] * v[0] + v[1] * v[1] + v[2] * v[2] + v[3] * v[3];
#pragma unroll
  for (int off = 32; off > 0; off >>= 1) {
    s += __shfl_down(s, off, 64);
    q += __shfl_down(q, off, 64);
  }
  __shared__ float red[8];
  if (lane == 0) { red[w] = s; red[w + 4] = q; }
  __syncthreads();
  s = red[0] + red[1] + red[2] + red[3];
  q = red[4] + red[5] + red[6] + red[7];
  const float mu = s * (1.f / D_DIM);
  const float var = q * (1.f / D_DIM) - mu * mu;
  const float rs = rsqrtf(var + 1e-5f);
  f32x4 g = *(const f32x4*)&gamma[tid * 4];
  f32x4 bb = *(const f32x4*)&beta[tid * 4];
  f32x4 o;
#pragma unroll
  for (int j = 0; j < 4; ++j) o[j] = (v[j] - mu) * rs * g[j] + bb[j];
  *(f32x4*)&outf[row * D_DIM + tid * 4] = o;
  if constexpr (WRITE_BF16) {
    short4_t ob;
#pragma unroll
    for (int j = 0; j < 4; ++j) ob[j] = (short)f2bf(o[j]);
    *(short4_t*)&outb[row * D_DIM + tid * 4] = ob;
  }
}

__global__ __launch_bounds__(256) void cast_kernel(
    const float* __restrict__ in, unsigned short* __restrict__ out, long n) {
  long i = ((long)blockIdx.x * 256 + threadIdx.x) * 8;
  if (i >= n) return;
  f32x4 a = *(const f32x4*)&in[i];
  f32x4 b = *(const f32x4*)&in[i + 4];
  short8 v;
#pragma unroll
  for (int j = 0; j < 4; ++j) v[j] = (short)f2bf(a[j]);
#pragma unroll
  for (int j = 0; j < 4; ++j) v[4 + j] = (short)f2bf(b[j]);
  *(short8*)&out[i] = v;
}

// ---------------------------------------------------------------------------
// Workspace plan (MB offsets; 240 MB peak). Timeline-checked (same as R5-R8):
//   0-8 w1b, 8-16 w2b (persist)
//   16-80  srcb(16-48, dead@QKV) -> Kt(16-48)/Vt(48-80, dead@KV)
//          -> AO fp32 (written@AO, LN1 in-place) = X (lives to FFN2)
//   80-112 KVm(80-96, dead@Mt), Mt(96-112, dead@AO) -> Xb (written@LN1)
//   112-240 wqkvb(112-118)+bqkv(118-119)+wob(119-121) dead@Mt;
//          QKVb(144-240, written@QKV, Q-slice read@AO, dead after)
//          -> H (written@FFN1)
// ---------------------------------------------------------------------------
extern "C" void kernel_launch(void* const* d_in, const int* in_sizes, int n_in,
                              void* d_out, int out_size, void* d_ws, size_t ws_size,
                              hipStream_t stream) {
  const float* src = (const float*)d_in[0];
  const float* wq  = (const float*)d_in[1];
  const float* bq  = (const float*)d_in[2];
  const float* wk  = (const float*)d_in[3];
  const float* bk  = (const float*)d_in[4];
  const float* wv  = (const float*)d_in[5];
  const float* bv  = (const float*)d_in[6];
  const float* wo  = (const float*)d_in[7];
  const float* bo  = (const float*)d_in[8];
  const float* w1  = (const float*)d_in[9];
  const float* b1  = (const float*)d_in[10];
  const float* w2  = (const float*)d_in[11];
  const float* b2  = (const float*)d_in[12];
  const float* g1  = (const float*)d_in[13];
  const float* be1 = (const float*)d_in[14];
  const float* g2  = (const float*)d_in[15];
  const float* be2 = (const float*)d_in[16];

  const long MB = 1024L * 1024L;
  if (ws_size < 248 * MB) return;
  char* ws = (char*)d_ws;
  unsigned short* w1b   = (unsigned short*)(ws + 0 * MB);
  unsigned short* w2b   = (unsigned short*)(ws + 8 * MB);
  unsigned short* srcb  = (unsigned short*)(ws + 16 * MB);
  unsigned short* Kt    = (unsigned short*)(ws + 16 * MB);   // after srcb dead
  unsigned short* Vt    = (unsigned short*)(ws + 48 * MB);
  float*          AO    = (float*)(ws + 16 * MB);            // after Kt/Vt dead
  float*          X     = (float*)(ws + 16 * MB);            // LN1 in-place
  unsigned short* KVm   = (unsigned short*)(ws + 80 * MB);
  unsigned short* Mt    = (unsigned short*)(ws + 96 * MB);
  unsigned short* Xb    = (unsigned short*)(ws + 80 * MB);   // after KVm/Mt dead
  unsigned short* wqkvb = (unsigned short*)(ws + 112 * MB);  // 6 MB
  float*          bqkv  = (float*)(ws + 118 * MB);           // 12 KB
  unsigned short* wob   = (unsigned short*)(ws + 119 * MB);  // 2 MB
  unsigned short* QKVb  = (unsigned short*)(ws + 144 * MB);  // 96 MB
  unsigned short* H     = (unsigned short*)(ws + 112 * MB);  // after QKV dead

  const dim3 blk(256);
  const dim3 blk512(512);
  // casts + packed bias
  cast_kernel<<<dim3(512), blk, 0, stream>>>(wq, wqkvb, 1048576);
  cast_kernel<<<dim3(512), blk, 0, stream>>>(wk, wqkvb + 1048576, 1048576);
  cast_kernel<<<dim3(512), blk, 0, stream>>>(wv, wqkvb + 2097152, 1048576);
  cast_kernel<<<dim3(512), blk, 0, stream>>>(wo, wob, 1048576);
  cast_kernel<<<dim3(2048), blk, 0, stream>>>(w1, w1b, 4194304);
  cast_kernel<<<dim3(2048), blk, 0, stream>>>(w2, w2b, 4194304);
  cast_kernel<<<dim3(8192), blk, 0, stream>>>(src, srcb, 16777216);
  hipMemcpyAsync(bqkv, bq, 4096, hipMemcpyDeviceToDevice, stream);
  hipMemcpyAsync(bqkv + 1024, bk, 4096, hipMemcpyDeviceToDevice, stream);
  hipMemcpyAsync(bqkv + 2048, bv, 4096, hipMemcpyDeviceToDevice, stream);

  // fused QKV: [16384,1024] @ [3072,1024]^T -> QKVb [16384,3072]
  gemm256_kernel<5><<<dim3(12, 64, 1), blk512, 0, stream>>>(
      srcb, 1024, 0, wqkvb, 1024, 0, QKVb, 3072, 0, bqkv, nullptr, 0, 0, 1024);

  // per-batch transposes of K,V slices -> [B][D][S]
  transpose_kernel<<<dim3(32, 16, 8), blk, 0, stream>>>(QKVb + 1024, Kt, 3072);
  transpose_kernel<<<dim3(32, 16, 8), blk, 0, stream>>>(QKVb + 2048, Vt, 3072);

  // KV[d,f] = sum_s Kt[d,s]*Vt[f,s]  (M=N=1024, K=2048, batch 8) -- 128^2
  gemm_bt_kernel<0><<<dim3(8, 8, 8), blk, 0, stream>>>(
      Kt, 2048, 2097152, Vt, 2048, 2097152, KVm, 1024, 1048576,
      nullptr, nullptr, 0, 0, 2048);
  // Mt[e,d] = sum_f wo[e,f]*KV[d,f]  (M=N=1024, K=1024, batch 8) -- 128^2
  gemm_bt_kernel<0><<<dim3(8, 8, 8), blk, 0, stream>>>(
      wob, 1024, 0, KVm, 1024, 1048576, Mt, 1024, 1048576,
      nullptr, nullptr, 0, 0, 1024);
  // AO[s,b,e] = sum_d Q[s,b,d]*Mt[e,d] + bo[e] + src  (Q read from QKVb)
  gemm256_kernel<4><<<dim3(4, 8, 8), blk512, 0, stream>>>(
      QKVb, 24576, 3072, Mt, 1024, 1048576, AO, 8192, 1024,
      bo, src, 8192, 1024, 1024);

  // x = LN(AO) in-place -> X fp32 + Xb bf16
  layernorm_kernel<1><<<dim3(16384), blk, 0, stream>>>(AO, X, Xb, g1, be1);

  // FFN, full M=16384
  gemm256_kernel<3><<<dim3(16, 64, 1), blk512, 0, stream>>>(
      Xb, 1024, 0, w1b, 1024, 0, H, 4096, 0, b1, nullptr, 0, 0, 1024);
  gemm256_kernel<4><<<dim3(4, 64, 1), blk512, 0, stream>>>(
      H, 4096, 0, w2b, 4096, 0, (float*)d_out, 1024, 0,
      b2, X, 1024, 0, 4096);

  // final LN in-place on d_out
  layernorm_kernel<0><<<dim3(16384), blk, 0, stream>>>(
      (float*)d_out, (float*)d_out, nullptr, g2, be2);
}

// Round 10
// 626.504 us; speedup vs baseline: 1.0526x; 1.0385x over previous
//
#include <hip/hip_runtime.h>
#include <hip/hip_bf16.h>
#include <math.h>

// ---------------------------------------------------------------------------
// CustomTransformerEncoderLayer (linear attention, ELU+1 feature map)
// S=2048 B=8 D=1024 F=4096, fp32 in/out, bf16 MFMA internals.
//
// Round 10: pipeline-level cuts (GEMM K-loop byte-identical to passing R9;
// four schedule variants all measured 41-42% MfmaUtil -> GEMM internals
// closed). (1) KV+Mt move to gemm256 (EPI=0): ~35/18us/block-bound vs the
// slower 128^2 path. (2) fp32 X/AO intermediates dropped: AO writes bf16
// (EPI=7), LN1 is bf16->bf16, FFN2 residual reads bf16 (EPI=6) -- saves
// ~192MB HBM traffic. 128^2 kernel deleted.
// ---------------------------------------------------------------------------

typedef __attribute__((ext_vector_type(8))) short short8;
typedef __attribute__((ext_vector_type(4))) short short4_t;
typedef __attribute__((ext_vector_type(4))) float f32x4;

#define S_DIM 2048
#define B_DIM 8
#define D_DIM 1024
#define F_DIM 4096

__device__ __forceinline__ unsigned short f2bf(float f) {
  __hip_bfloat16 h = __float2bfloat16(f);
  return *reinterpret_cast<unsigned short*>(&h);
}
__device__ __forceinline__ float bf2f(unsigned short u) {
  return __bfloat162float(*reinterpret_cast<const __hip_bfloat16*>(&u));
}

#define GLD16(gp, sp)                                              \
  __builtin_amdgcn_global_load_lds(                                \
      (const __attribute__((address_space(1))) void*)(gp),         \
      (__attribute__((address_space(3))) void*)(sp), 16, 0, 0)

#define BAR()                                  \
  do {                                         \
    asm volatile("" ::: "memory");             \
    __builtin_amdgcn_s_barrier();              \
    asm volatile("" ::: "memory");             \
  } while (0)
#define WAITVM6() asm volatile("s_waitcnt vmcnt(6)" ::: "memory")
#define WAITVM10() asm volatile("s_waitcnt vmcnt(10)" ::: "memory")
#define WAITVM0() asm volatile("s_waitcnt vmcnt(0)" ::: "memory")
// rule 18: lgkmcnt(0) then sched_barrier(0) so MFMAs can't hoist above it.
#define LGKM0_FENCE()                                        \
  do {                                                       \
    asm volatile("s_waitcnt lgkmcnt(0)" ::: "memory");       \
    __builtin_amdgcn_sched_barrier(0);                       \
  } while (0)

// ---------------------------------------------------------------------------
// gemm256: C[i,j] = sum_k A[i,k]*B[j,k], BM=BN=256, BK=64, 512 thr (8 waves
// 2Mx4N), per-wave 128x64 output. 8-phase K-loop, double-buffered 128KiB LDS,
// chunk^row XOR swizzle (0 bank conflicts), vmcnt(6) at ph3/ph7 only.
// Requires M%256==0, N%256==0, K%128==0, K>=256, gridDim.x*gridDim.y%8==0.
// (K-loop identical to R9; see R9 header for the schedule/wait audit.)
// EPI: 0 ->bf16 (no bias), 3 relu+bias->bf16, 5 bias+(col<2048?elu)->bf16,
//      6 bias+bf16resid->fp32, 7 bias+fp32resid->bf16
// ---------------------------------------------------------------------------
template <int EPI>
__global__ __launch_bounds__(512, 2) void gemm256_kernel(
    const unsigned short* __restrict__ A, long lda, long sA,
    const unsigned short* __restrict__ B, long ldb, long sB,
    void* __restrict__ Cv, long ldc, long sC,
    const float* __restrict__ bias,
    const void* __restrict__ residv, long ldr, long sR, int K) {
  __shared__ short lds[65536];  // 128 KiB
  // T1 XCD swizzle
  const int gx = gridDim.x;
  const int nwg = gx * gridDim.y;
  const int orig = blockIdx.y * gx + blockIdx.x;
  const int cpx = nwg >> 3;
  const int wgid = (orig & 7) * cpx + (orig >> 3);
  const int bx = wgid % gx, by = wgid / gx;
  const int bz = blockIdx.z;
  const unsigned short* Ablk = A + (long)bz * sA + (long)by * 256 * lda;
  const unsigned short* Bblk = B + (long)bz * sB + (long)bx * 256 * ldb;

  const int tid = threadIdx.x;
  const int w = tid >> 6, lane = tid & 63;
  const int wm = w >> 2, wn = w & 3;
  const int lr = lane & 15, kh = lane >> 4;

  // staging geometry (2 global_load_lds per thread per quarter-region)
  const int sr = w * 8 + (lane >> 3);              // l=0 local row (0..63)
  const int sc = ((lane & 7) ^ (lane >> 3)) * 8;   // inverse-swizzled src col
  const int br0 = sr + ((sr >> 5) << 5);
  // base pointers (advanced +128 elems per main-loop iteration)
  const unsigned short* pA = Ablk + (long)sr * lda + sc;   // A h=0, load0
  const unsigned short* pB = Bblk + (long)br0 * ldb + sc;  // B nh=0, load0
  // wave-uniform deltas (SGPR): load1 = +128 rows for both A and B
  const long dA1 = 128 * lda, dAh = 64 * lda;
  const long dB1 = 128 * ldb, dBh = 32 * ldb;
  const int dst0 = w * 1024;
  const int dst1 = (8 + w) * 1024;

#define STAGE_A(bufOff, h, rel)                                               \
  do {                                                                        \
    GLD16(pA + (h) * dAh + (rel) * 64,                                        \
          (char*)lds + (bufOff) + (h)*16384 + dst0);                          \
    GLD16(pA + (h) * dAh + dA1 + (rel) * 64,                                  \
          (char*)lds + (bufOff) + (h)*16384 + dst1);                          \
  } while (0)
#define STAGE_B(bufOff, nh, rel)                                              \
  do {                                                                        \
    GLD16(pB + (nh) * dBh + (rel) * 64,                                       \
          (char*)lds + (bufOff) + 32768 + (nh)*16384 + dst0);                 \
    GLD16(pB + (nh) * dBh + dB1 + (rel) * 64,                                 \
          (char*)lds + (bufOff) + 32768 + (nh)*16384 + dst1);                 \
  } while (0)

  // fragment-read geometry
  const int chk0 = ((kh ^ (lr & 7)) << 4);
  const int chk1 = (((4 + kh) ^ (lr & 7)) << 4);
  const int aRdBase = (wm * 64 + lr) * 128;
  const int bRdBase = (wn * 32 + lr) * 128;

  short8 af[4][2], b0r[2][2], b1r[2][2];
  f32x4 acc[8][4];
#pragma unroll
  for (int m = 0; m < 8; ++m)
#pragma unroll
    for (int n = 0; n < 4; ++n)
#pragma unroll
      for (int j = 0; j < 4; ++j) acc[m][n][j] = 0.f;

#define LDA_H(bufOff, h)                                                     \
  do {                                                                       \
    const char* _p = (const char*)lds + (bufOff) + (h)*16384 + aRdBase;      \
    _Pragma("unroll") for (int m = 0; m < 4; ++m) {                          \
      af[m][0] = *(const short8*)(_p + m * 2048 + chk0);                     \
      af[m][1] = *(const short8*)(_p + m * 2048 + chk1);                     \
    }                                                                        \
  } while (0)
#define LDB_H(dst, bufOff, nh)                                               \
  do {                                                                       \
    const char* _p = (const char*)lds + (bufOff) + 32768 + (nh)*16384 + bRdBase; \
    _Pragma("unroll") for (int n = 0; n < 2; ++n) {                          \
      dst[n][0] = *(const short8*)(_p + n * 2048 + chk0);                    \
      dst[n][1] = *(const short8*)(_p + n * 2048 + chk1);                    \
    }                                                                        \
  } while (0)
#define MFMA_Q(mh, nh, bset)                                                 \
  do {                                                                       \
    __builtin_amdgcn_s_setprio(1);                                           \
    _Pragma("unroll") for (int m = 0; m < 4; ++m)                            \
    _Pragma("unroll") for (int n = 0; n < 2; ++n)                            \
    _Pragma("unroll") for (int ks = 0; ks < 2; ++ks)                         \
      acc[(mh)*4 + m][(nh)*2 + n] = __builtin_amdgcn_mfma_f32_16x16x32_bf16( \
          af[m][ks], bset[n][ks], acc[(mh)*4 + m][(nh)*2 + n], 0, 0, 0);     \
    __builtin_amdgcn_s_setprio(0);                                           \
  } while (0)

  const int T = K >> 6;  // T even, >=4
  // prologue FIFO: t0.{A0,B0,B1,A1} -> buf0, t1.{A0,B0,B1} -> buf1.
  STAGE_A(0, 0, 0); STAGE_B(0, 0, 0); STAGE_B(0, 1, 0); STAGE_A(0, 1, 0);
  STAGE_A(65536, 0, 1); STAGE_B(65536, 0, 1); STAGE_B(65536, 1, 1);
  WAITVM10(); BAR();
  LDB_H(b0r, 0, 0);  // preload even-tile B0

  for (int i = 0; i < (T >> 1) - 1; ++i) {
    // ph0
    LDA_H(0, 0); STAGE_A(65536, 1, 1);
    BAR(); LGKM0_FENCE(); MFMA_Q(0, 0, b0r); BAR();
    // ph1
    LDB_H(b1r, 0, 1); STAGE_A(0, 0, 2);
    BAR(); LGKM0_FENCE(); MFMA_Q(0, 1, b1r); BAR();
    // ph2
    LDA_H(0, 1); STAGE_B(0, 0, 2);
    BAR(); LGKM0_FENCE(); MFMA_Q(1, 1, b1r); BAR();
    // ph3: vmcnt(6) lands the odd tile; post-MFMA read of b1.B0.
    STAGE_B(0, 1, 2);
    WAITVM6(); BAR(); MFMA_Q(1, 0, b0r); LDB_H(b0r, 65536, 0); BAR();
    // ph4
    LDA_H(65536, 0); STAGE_A(0, 1, 2);
    BAR(); LGKM0_FENCE(); MFMA_Q(0, 0, b0r); BAR();
    // ph5
    LDB_H(b1r, 65536, 1); STAGE_A(65536, 0, 3);
    BAR(); LGKM0_FENCE(); MFMA_Q(0, 1, b1r); BAR();
    // ph6
    LDA_H(65536, 1); STAGE_B(65536, 0, 3);
    BAR(); LGKM0_FENCE(); MFMA_Q(1, 1, b1r); BAR();
    // ph7: vmcnt(6) lands the next even tile; read b0.B0(rel2) post-MFMA.
    STAGE_B(65536, 1, 3);
    WAITVM6(); BAR(); MFMA_Q(1, 0, b0r); LDB_H(b0r, 0, 0); BAR();
    pA += 128; pB += 128;  // advance 2 K-tiles
  }

  // ---- peeled last iteration: tiles T-2 (buf0, rel0) and T-1 (buf1, rel1).
  // ph0 stages the one missing quarter (T-1's A1); vmcnt(0) at peel ph3.
  LDA_H(0, 0); STAGE_A(65536, 1, 1);
  BAR(); LGKM0_FENCE(); MFMA_Q(0, 0, b0r); BAR();
  LDB_H(b1r, 0, 1);
  BAR(); LGKM0_FENCE(); MFMA_Q(0, 1, b1r); BAR();
  LDA_H(0, 1);
  BAR(); LGKM0_FENCE(); MFMA_Q(1, 1, b1r); BAR();
  WAITVM0(); BAR(); MFMA_Q(1, 0, b0r); LDB_H(b0r, 65536, 0); BAR();
  LDA_H(65536, 0);
  BAR(); LGKM0_FENCE(); MFMA_Q(0, 0, b0r); BAR();
  LDB_H(b1r, 65536, 1);
  BAR(); LGKM0_FENCE(); MFMA_Q(0, 1, b1r); BAR();
  LDA_H(65536, 1);
  BAR(); LGKM0_FENCE(); MFMA_Q(1, 1, b1r); BAR();
  LGKM0_FENCE(); MFMA_Q(1, 0, b0r);

  // C/D layout: col = lane&15, row = kh*4 + j
  const long gm0 = (long)by * 256 + wm * 128;
  const long gn0 = (long)bx * 256 + wn * 64;
  if constexpr (EPI == 6) {
    // bias + bf16 residual -> fp32 out
    float* C = (float*)Cv + (long)bz * sC;
    const unsigned short* R = (const unsigned short*)residv + (long)bz * sR;
#pragma unroll
    for (int mg = 0; mg < 8; ++mg)
#pragma unroll
      for (int ng = 0; ng < 4; ++ng) {
        const long col = gn0 + ng * 16 + lr;
        const float bcol = bias[col];
#pragma unroll
        for (int j = 0; j < 4; ++j) {
          const long row = gm0 + mg * 16 + kh * 4 + j;
          C[row * ldc + col] = acc[mg][ng][j] + bcol + bf2f(R[row * ldr + col]);
        }
      }
  } else if constexpr (EPI == 7) {
    // bias + fp32 residual -> bf16 out
    unsigned short* C = (unsigned short*)Cv + (long)bz * sC;
    const float* R = (const float*)residv + (long)bz * sR;
#pragma unroll
    for (int mg = 0; mg < 8; ++mg)
#pragma unroll
      for (int ng = 0; ng < 4; ++ng) {
        const long col = gn0 + ng * 16 + lr;
        const float bcol = bias[col];
#pragma unroll
        for (int j = 0; j < 4; ++j) {
          const long row = gm0 + mg * 16 + kh * 4 + j;
          C[row * ldc + col] = f2bf(acc[mg][ng][j] + bcol + R[row * ldr + col]);
        }
      }
  } else {
    unsigned short* C = (unsigned short*)Cv + (long)bz * sC;
    const bool do_elu = (EPI == 5) && (gn0 < 2048);  // wave-uniform segment
#pragma unroll
    for (int mg = 0; mg < 8; ++mg)
#pragma unroll
      for (int ng = 0; ng < 4; ++ng) {
        const long col = gn0 + ng * 16 + lr;
        float bcol = 0.f;
        if constexpr (EPI != 0) bcol = bias[col];
#pragma unroll
        for (int j = 0; j < 4; ++j) {
          const long row = gm0 + mg * 16 + kh * 4 + j;
          float v = acc[mg][ng][j] + bcol;
          if constexpr (EPI == 3) v = fmaxf(v, 0.f);  // relu
          if constexpr (EPI == 5) {
            if (do_elu) v = (v > 0.f) ? (v + 1.f) : expf(v);  // elu+1
          }
          C[row * ldc + col] = f2bf(v);
        }
      }
  }
#undef STAGE_A
#undef STAGE_B
#undef LDA_H
#undef LDB_H
#undef MFMA_Q
}

// ---------------------------------------------------------------------------
// transpose: in rows indexed (s*8+b) with element stride ld -> out [B][D][S].
// grid (S/64, D/64, B), 256 threads, LDS 64x68 tile.
// ---------------------------------------------------------------------------
__global__ __launch_bounds__(256) void transpose_kernel(
    const unsigned short* __restrict__ in, unsigned short* __restrict__ out,
    long ld) {
  __shared__ unsigned short t[64][68];
  const int b = blockIdx.z;
  const long s0 = (long)blockIdx.x * 64, d0 = (long)blockIdx.y * 64;
  const int tid = threadIdx.x;
  {
    const int r = tid >> 3, c = (tid & 7) * 8;
#pragma unroll
    for (int it = 0; it < 2; ++it) {
      const int s = r + it * 32;
      const unsigned short* g = &in[((s0 + s) * B_DIM + b) * ld + d0 + c];
      short4_t v0 = *(const short4_t*)g;
      short4_t v1 = *(const short4_t*)(g + 4);
      *(short4_t*)&t[s][c] = v0;
      *(short4_t*)&t[s][c + 4] = v1;
    }
  }
  __syncthreads();
  {
    const int d = tid >> 3, c = (tid & 7) * 8;
#pragma unroll
    for (int it = 0; it < 2; ++it) {
      const int dd = d + it * 32;
      short8 v;
#pragma unroll
      for (int j = 0; j < 8; ++j) v[j] = (short)t[c + j][dd];
      *(short8*)&out[(long)b * ((long)D_DIM * S_DIM) + (d0 + dd) * S_DIM + s0 + c] = v;
    }
  }
}

// ---------------------------------------------------------------------------
// layernorm fp32 in-place over last dim (1024). One block per row.
// ---------------------------------------------------------------------------
__global__ __launch_bounds__(256) void layernorm_kernel(
    const float* in, float* outf,
    const float* __restrict__ gamma, const float* __restrict__ beta) {
  const long row = blockIdx.x;
  const float* x = in + row * D_DIM;
  const int tid = threadIdx.x;
  const int lane = tid & 63, w = tid >> 6;
  f32x4 v = *(const f32x4*)&x[tid * 4];
  float s = v[0] + v[1] + v[2] + v[3];
  float q = v[0] * v[0] + v[1] * v[1] + v[2] * v[2] + v[3] * v[3];
#pragma unroll
  for (int off = 32; off > 0; off >>= 1) {
    s += __shfl_down(s, off, 64);
    q += __shfl_down(q, off, 64);
  }
  __shared__ float red[8];
  if (lane == 0) { red[w] = s; red[w + 4] = q; }
  __syncthreads();
  s = red[0] + red[1] + red[2] + red[3];
  q = red[4] + red[5] + red[6] + red[7];
  const float mu = s * (1.f / D_DIM);
  const float var = q * (1.f / D_DIM) - mu * mu;
  const float rs = rsqrtf(var + 1e-5f);
  f32x4 g = *(const f32x4*)&gamma[tid * 4];
  f32x4 bb = *(const f32x4*)&beta[tid * 4];
  f32x4 o;
#pragma unroll
  for (int j = 0; j < 4; ++j) o[j] = (v[j] - mu) * rs * g[j] + bb[j];
  *(f32x4*)&outf[row * D_DIM + tid * 4] = o;
}

// ---------------------------------------------------------------------------
// layernorm bf16 -> bf16 over last dim (1024). One block per row.
// ---------------------------------------------------------------------------
__global__ __launch_bounds__(256) void layernorm_bf_kernel(
    const unsigned short* __restrict__ in, unsigned short* __restrict__ out,
    const float* __restrict__ gamma, const float* __restrict__ beta) {
  const long row = blockIdx.x;
  const int tid = threadIdx.x;
  const int lane = tid & 63, w = tid >> 6;
  short4_t r4 = *(const short4_t*)&in[row * D_DIM + tid * 4];
  f32x4 v;
#pragma unroll
  for (int j = 0; j < 4; ++j) v[j] = bf2f((unsigned short)r4[j]);
  float s = v[0] + v[1] + v[2] + v[3];
  float q = v[0] * v[0] + v[1] * v[1] + v[2] * v[2] + v[3] * v[3];
#pragma unroll
  for (int off = 32; off > 0; off >>= 1) {
    s += __shfl_down(s, off, 64);
    q += __shfl_down(q, off, 64);
  }
  __shared__ float red[8];
  if (lane == 0) { red[w] = s; red[w + 4] = q; }
  __syncthreads();
  s = red[0] + red[1] + red[2] + red[3];
  q = red[4] + red[5] + red[6] + red[7];
  const float mu = s * (1.f / D_DIM);
  const float var = q * (1.f / D_DIM) - mu * mu;
  const float rs = rsqrtf(var + 1e-5f);
  f32x4 g = *(const f32x4*)&gamma[tid * 4];
  f32x4 bb = *(const f32x4*)&beta[tid * 4];
  short4_t ob;
#pragma unroll
  for (int j = 0; j < 4; ++j)
    ob[j] = (short)f2bf((v[j] - mu) * rs * g[j] + bb[j]);
  *(short4_t*)&out[row * D_DIM + tid * 4] = ob;
}

__global__ __launch_bounds__(256) void cast_kernel(
    const float* __restrict__ in, unsigned short* __restrict__ out, long n) {
  long i = ((long)blockIdx.x * 256 + threadIdx.x) * 8;
  if (i >= n) return;
  f32x4 a = *(const f32x4*)&in[i];
  f32x4 b = *(const f32x4*)&in[i + 4];
  short8 v;
#pragma unroll
  for (int j = 0; j < 4; ++j) v[j] = (short)f2bf(a[j]);
#pragma unroll
  for (int j = 0; j < 4; ++j) v[4 + j] = (short)f2bf(b[j]);
  *(short8*)&out[i] = v;
}

// ---------------------------------------------------------------------------
// Workspace plan (MB offsets; 240 MB peak). Timeline-checked:
//   0-8 w1b, 8-16 w2b (persist)
//   16-48  srcb (dead@QKV) -> Kt (dead@KV) -> AOb bf16 (dead@LN1)
//   48-80  Vt (dead@KV) -> Xb bf16 (read@FFN1 A, @FFN2 resid)
//   80-96  KVm (dead@Mt) | 96-112 Mt (dead@AO)
//   112-240 wqkvb(112-118)+bqkv(118-119)+wob(119-121) dead@Mt;
//           QKVb(144-240, dead@AO) -> H(112-240, written@FFN1)
// ---------------------------------------------------------------------------
extern "C" void kernel_launch(void* const* d_in, const int* in_sizes, int n_in,
                              void* d_out, int out_size, void* d_ws, size_t ws_size,
                              hipStream_t stream) {
  const float* src = (const float*)d_in[0];
  const float* wq  = (const float*)d_in[1];
  const float* bq  = (const float*)d_in[2];
  const float* wk  = (const float*)d_in[3];
  const float* bk  = (const float*)d_in[4];
  const float* wv  = (const float*)d_in[5];
  const float* bv  = (const float*)d_in[6];
  const float* wo  = (const float*)d_in[7];
  const float* bo  = (const float*)d_in[8];
  const float* w1  = (const float*)d_in[9];
  const float* b1  = (const float*)d_in[10];
  const float* w2  = (const float*)d_in[11];
  const float* b2  = (const float*)d_in[12];
  const float* g1  = (const float*)d_in[13];
  const float* be1 = (const float*)d_in[14];
  const float* g2  = (const float*)d_in[15];
  const float* be2 = (const float*)d_in[16];

  const long MB = 1024L * 1024L;
  if (ws_size < 248 * MB) return;
  char* ws = (char*)d_ws;
  unsigned short* w1b   = (unsigned short*)(ws + 0 * MB);
  unsigned short* w2b   = (unsigned short*)(ws + 8 * MB);
  unsigned short* srcb  = (unsigned short*)(ws + 16 * MB);
  unsigned short* Kt    = (unsigned short*)(ws + 16 * MB);   // after srcb dead
  unsigned short* AOb   = (unsigned short*)(ws + 16 * MB);   // after Kt dead
  unsigned short* Vt    = (unsigned short*)(ws + 48 * MB);
  unsigned short* Xb    = (unsigned short*)(ws + 48 * MB);   // after Vt dead
  unsigned short* KVm   = (unsigned short*)(ws + 80 * MB);
  unsigned short* Mt    = (unsigned short*)(ws + 96 * MB);
  unsigned short* wqkvb = (unsigned short*)(ws + 112 * MB);  // 6 MB
  float*          bqkv  = (float*)(ws + 118 * MB);           // 12 KB
  unsigned short* wob   = (unsigned short*)(ws + 119 * MB);  // 2 MB
  unsigned short* QKVb  = (unsigned short*)(ws + 144 * MB);  // 96 MB
  unsigned short* H     = (unsigned short*)(ws + 112 * MB);  // after QKV dead

  const dim3 blk(256);
  const dim3 blk512(512);
  // casts + packed bias
  cast_kernel<<<dim3(512), blk, 0, stream>>>(wq, wqkvb, 1048576);
  cast_kernel<<<dim3(512), blk, 0, stream>>>(wk, wqkvb + 1048576, 1048576);
  cast_kernel<<<dim3(512), blk, 0, stream>>>(wv, wqkvb + 2097152, 1048576);
  cast_kernel<<<dim3(512), blk, 0, stream>>>(wo, wob, 1048576);
  cast_kernel<<<dim3(2048), blk, 0, stream>>>(w1, w1b, 4194304);
  cast_kernel<<<dim3(2048), blk, 0, stream>>>(w2, w2b, 4194304);
  cast_kernel<<<dim3(8192), blk, 0, stream>>>(src, srcb, 16777216);
  hipMemcpyAsync(bqkv, bq, 4096, hipMemcpyDeviceToDevice, stream);
  hipMemcpyAsync(bqkv + 1024, bk, 4096, hipMemcpyDeviceToDevice, stream);
  hipMemcpyAsync(bqkv + 2048, bv, 4096, hipMemcpyDeviceToDevice, stream);

  // fused QKV: [16384,1024] @ [3072,1024]^T -> QKVb [16384,3072]
  gemm256_kernel<5><<<dim3(12, 64, 1), blk512, 0, stream>>>(
      srcb, 1024, 0, wqkvb, 1024, 0, QKVb, 3072, 0, bqkv, nullptr, 0, 0, 1024);

  // per-batch transposes of K,V slices -> [B][D][S]
  transpose_kernel<<<dim3(32, 16, 8), blk, 0, stream>>>(QKVb + 1024, Kt, 3072);
  transpose_kernel<<<dim3(32, 16, 8), blk, 0, stream>>>(QKVb + 2048, Vt, 3072);

  // KV[d,f] = sum_s Kt[d,s]*Vt[f,s]  (M=N=1024, K=2048, batch 8)
  gemm256_kernel<0><<<dim3(4, 4, 8), blk512, 0, stream>>>(
      Kt, 2048, 2097152, Vt, 2048, 2097152, KVm, 1024, 1048576,
      nullptr, nullptr, 0, 0, 2048);
  // Mt[e,d] = sum_f wo[e,f]*KV[d,f]  (M=N=1024, K=1024, batch 8)
  gemm256_kernel<0><<<dim3(4, 4, 8), blk512, 0, stream>>>(
      wob, 1024, 0, KVm, 1024, 1048576, Mt, 1024, 1048576,
      nullptr, nullptr, 0, 0, 1024);
  // AO[s,b,e] = sum_d Q[s,b,d]*Mt[e,d] + bo[e] + src -> bf16 AOb
  gemm256_kernel<7><<<dim3(4, 8, 8), blk512, 0, stream>>>(
      QKVb, 24576, 3072, Mt, 1024, 1048576, AOb, 8192, 1024,
      bo, src, 8192, 1024, 1024);

  // x = LN(AOb) -> Xb bf16
  layernorm_bf_kernel<<<dim3(16384), blk, 0, stream>>>(AOb, Xb, g1, be1);

  // FFN, full M=16384
  gemm256_kernel<3><<<dim3(16, 64, 1), blk512, 0, stream>>>(
      Xb, 1024, 0, w1b, 1024, 0, H, 4096, 0, b1, nullptr, 0, 0, 1024);
  gemm256_kernel<6><<<dim3(4, 64, 1), blk512, 0, stream>>>(
      H, 4096, 0, w2b, 4096, 0, (float*)d_out, 1024, 0,
      b2, Xb, 1024, 0, 4096);

  // final LN in-place on d_out
  layernorm_kernel<<<dim3(16384), blk, 0, stream>>>(
      (float*)d_out, (float*)d_out, g2, be2);
}

// Round 11
// 609.738 us; speedup vs baseline: 1.0815x; 1.0275x over previous
//
#include <hip/hip_runtime.h>
#include <hip/hip_bf16.h>
#include <math.h>

// ---------------------------------------------------------------------------
// CustomTransformerEncoderLayer (linear attention, ELU+1 feature map)
// S=2048 B=8 D=1024 F=4096, fp32 in/out, bf16 MFMA internals.
//
// Round 11: (1) remove the manual lgkmcnt(0)+sched_barrier wall before each
// MFMA cluster -- the af ds_reads are compiler-visible, so hipcc emits
// fine-grained lgkmcnt(N) and can overlap early MFMAs with late reads
// (rule 18's fence is only required for inline-asm ds_reads; mine aren't).
// MFMA_Q reordered ks-outer (acc dep distance 8). (2) FFN2 writes bf16
// (EPI 8) and LN2 is bf16->fp32: saves 64 MB HBM. vmcnt schedule, swizzle,
// staging, barriers byte-identical to the passing R9/R10 K-loop.
// ---------------------------------------------------------------------------

typedef __attribute__((ext_vector_type(8))) short short8;
typedef __attribute__((ext_vector_type(4))) short short4_t;
typedef __attribute__((ext_vector_type(4))) float f32x4;

#define S_DIM 2048
#define B_DIM 8
#define D_DIM 1024
#define F_DIM 4096

__device__ __forceinline__ unsigned short f2bf(float f) {
  __hip_bfloat16 h = __float2bfloat16(f);
  return *reinterpret_cast<unsigned short*>(&h);
}
__device__ __forceinline__ float bf2f(unsigned short u) {
  return __bfloat162float(*reinterpret_cast<const __hip_bfloat16*>(&u));
}

#define GLD16(gp, sp)                                              \
  __builtin_amdgcn_global_load_lds(                                \
      (const __attribute__((address_space(1))) void*)(gp),         \
      (__attribute__((address_space(3))) void*)(sp), 16, 0, 0)

#define BAR()                                  \
  do {                                         \
    asm volatile("" ::: "memory");             \
    __builtin_amdgcn_s_barrier();              \
    asm volatile("" ::: "memory");             \
  } while (0)
#define WAITVM6() asm volatile("s_waitcnt vmcnt(6)" ::: "memory")
#define WAITVM10() asm volatile("s_waitcnt vmcnt(10)" ::: "memory")
#define WAITVM0() asm volatile("s_waitcnt vmcnt(0)" ::: "memory")

// ---------------------------------------------------------------------------
// gemm256: C[i,j] = sum_k A[i,k]*B[j,k], BM=BN=256, BK=64, 512 thr (8 waves
// 2Mx4N), per-wave 128x64 output. 8-phase K-loop, double-buffered 128KiB LDS,
// chunk^row XOR swizzle (0 bank conflicts), vmcnt(6) at ph3/ph7 only.
// Requires M%256==0, N%256==0, K%128==0, K>=256, gridDim.x*gridDim.y%8==0.
// LDS map: buf b at b*65536 B; A_h at h*16384, B_nh at 32768+nh*16384.
// Region slot(row r, chunk c') holds global chunk c = c' ^ (r&7) (16B chunks).
// Schedule identical to R9 (see its audit); the only K-loop delta: no manual
// lgkm fence -- compiler emits fine-grained lgkmcnt for the af->MFMA deps.
// EPI: 0 ->bf16 (no bias), 3 relu+bias->bf16, 5 bias+(col<2048?elu)->bf16,
//      7 bias+fp32resid->bf16, 8 bias+bf16resid->bf16
// ---------------------------------------------------------------------------
template <int EPI>
__global__ __launch_bounds__(512, 2) void gemm256_kernel(
    const unsigned short* __restrict__ A, long lda, long sA,
    const unsigned short* __restrict__ B, long ldb, long sB,
    void* __restrict__ Cv, long ldc, long sC,
    const float* __restrict__ bias,
    const void* __restrict__ residv, long ldr, long sR, int K) {
  __shared__ short lds[65536];  // 128 KiB
  // T1 XCD swizzle
  const int gx = gridDim.x;
  const int nwg = gx * gridDim.y;
  const int orig = blockIdx.y * gx + blockIdx.x;
  const int cpx = nwg >> 3;
  const int wgid = (orig & 7) * cpx + (orig >> 3);
  const int bx = wgid % gx, by = wgid / gx;
  const int bz = blockIdx.z;
  const unsigned short* Ablk = A + (long)bz * sA + (long)by * 256 * lda;
  const unsigned short* Bblk = B + (long)bz * sB + (long)bx * 256 * ldb;

  const int tid = threadIdx.x;
  const int w = tid >> 6, lane = tid & 63;
  const int wm = w >> 2, wn = w & 3;
  const int lr = lane & 15, kh = lane >> 4;

  // staging geometry (2 global_load_lds per thread per quarter-region)
  const int sr = w * 8 + (lane >> 3);              // l=0 local row (0..63)
  const int sc = ((lane & 7) ^ (lane >> 3)) * 8;   // inverse-swizzled src col
  const int br0 = sr + ((sr >> 5) << 5);
  // base pointers (advanced +128 elems per main-loop iteration)
  const unsigned short* pA = Ablk + (long)sr * lda + sc;   // A h=0, load0
  const unsigned short* pB = Bblk + (long)br0 * ldb + sc;  // B nh=0, load0
  // wave-uniform deltas (SGPR): load1 = +128 rows for both A and B
  const long dA1 = 128 * lda, dAh = 64 * lda;
  const long dB1 = 128 * ldb, dBh = 32 * ldb;
  const int dst0 = w * 1024;
  const int dst1 = (8 + w) * 1024;

#define STAGE_A(bufOff, h, rel)                                               \
  do {                                                                        \
    GLD16(pA + (h) * dAh + (rel) * 64,                                        \
          (char*)lds + (bufOff) + (h)*16384 + dst0);                          \
    GLD16(pA + (h) * dAh + dA1 + (rel) * 64,                                  \
          (char*)lds + (bufOff) + (h)*16384 + dst1);                          \
  } while (0)
#define STAGE_B(bufOff, nh, rel)                                              \
  do {                                                                        \
    GLD16(pB + (nh) * dBh + (rel) * 64,                                       \
          (char*)lds + (bufOff) + 32768 + (nh)*16384 + dst0);                 \
    GLD16(pB + (nh) * dBh + dB1 + (rel) * 64,                                 \
          (char*)lds + (bufOff) + 32768 + (nh)*16384 + dst1);                 \
  } while (0)

  // fragment-read geometry
  const int chk0 = ((kh ^ (lr & 7)) << 4);
  const int chk1 = (((4 + kh) ^ (lr & 7)) << 4);
  const int aRdBase = (wm * 64 + lr) * 128;
  const int bRdBase = (wn * 32 + lr) * 128;

  short8 af[4][2], b0r[2][2], b1r[2][2];
  f32x4 acc[8][4];
#pragma unroll
  for (int m = 0; m < 8; ++m)
#pragma unroll
    for (int n = 0; n < 4; ++n)
#pragma unroll
      for (int j = 0; j < 4; ++j) acc[m][n][j] = 0.f;

#define LDA_H(bufOff, h)                                                     \
  do {                                                                       \
    const char* _p = (const char*)lds + (bufOff) + (h)*16384 + aRdBase;      \
    _Pragma("unroll") for (int m = 0; m < 4; ++m) {                          \
      af[m][0] = *(const short8*)(_p + m * 2048 + chk0);                     \
      af[m][1] = *(const short8*)(_p + m * 2048 + chk1);                     \
    }                                                                        \
  } while (0)
#define LDB_H(dst, bufOff, nh)                                               \
  do {                                                                       \
    const char* _p = (const char*)lds + (bufOff) + 32768 + (nh)*16384 + bRdBase; \
    _Pragma("unroll") for (int n = 0; n < 2; ++n) {                          \
      dst[n][0] = *(const short8*)(_p + n * 2048 + chk0);                    \
      dst[n][1] = *(const short8*)(_p + n * 2048 + chk1);                    \
    }                                                                        \
  } while (0)
// ks-outer: consecutive MFMAs hit distinct acc registers (dep distance 8).
#define MFMA_Q(mh, nh, bset)                                                 \
  do {                                                                       \
    __builtin_amdgcn_s_setprio(1);                                           \
    _Pragma("unroll") for (int ks = 0; ks < 2; ++ks)                         \
    _Pragma("unroll") for (int m = 0; m < 4; ++m)                            \
    _Pragma("unroll") for (int n = 0; n < 2; ++n)                            \
      acc[(mh)*4 + m][(nh)*2 + n] = __builtin_amdgcn_mfma_f32_16x16x32_bf16( \
          af[m][ks], bset[n][ks], acc[(mh)*4 + m][(nh)*2 + n], 0, 0, 0);     \
    __builtin_amdgcn_s_setprio(0);                                           \
  } while (0)

  const int T = K >> 6;  // T even, >=4
  // prologue FIFO: t0.{A0,B0,B1,A1} -> buf0, t1.{A0,B0,B1} -> buf1.
  STAGE_A(0, 0, 0); STAGE_B(0, 0, 0); STAGE_B(0, 1, 0); STAGE_A(0, 1, 0);
  STAGE_A(65536, 0, 1); STAGE_B(65536, 0, 1); STAGE_B(65536, 1, 1);
  WAITVM10(); BAR();
  LDB_H(b0r, 0, 0);  // preload even-tile B0

  for (int i = 0; i < (T >> 1) - 1; ++i) {
    // ph0
    LDA_H(0, 0); STAGE_A(65536, 1, 1);
    BAR(); MFMA_Q(0, 0, b0r); BAR();
    // ph1
    LDB_H(b1r, 0, 1); STAGE_A(0, 0, 2);
    BAR(); MFMA_Q(0, 1, b1r); BAR();
    // ph2
    LDA_H(0, 1); STAGE_B(0, 0, 2);
    BAR(); MFMA_Q(1, 1, b1r); BAR();
    // ph3: vmcnt(6) lands the odd tile; post-MFMA read of b1.B0.
    STAGE_B(0, 1, 2);
    WAITVM6(); BAR(); MFMA_Q(1, 0, b0r); LDB_H(b0r, 65536, 0); BAR();
    // ph4
    LDA_H(65536, 0); STAGE_A(0, 1, 2);
    BAR(); MFMA_Q(0, 0, b0r); BAR();
    // ph5
    LDB_H(b1r, 65536, 1); STAGE_A(65536, 0, 3);
    BAR(); MFMA_Q(0, 1, b1r); BAR();
    // ph6
    LDA_H(65536, 1); STAGE_B(65536, 0, 3);
    BAR(); MFMA_Q(1, 1, b1r); BAR();
    // ph7: vmcnt(6) lands the next even tile; read b0.B0(rel2) post-MFMA.
    STAGE_B(65536, 1, 3);
    WAITVM6(); BAR(); MFMA_Q(1, 0, b0r); LDB_H(b0r, 0, 0); BAR();
    pA += 128; pB += 128;  // advance 2 K-tiles
  }

  // ---- peeled last iteration: tiles T-2 (buf0, rel0) and T-1 (buf1, rel1).
  // ph0 stages the one missing quarter (T-1's A1); vmcnt(0) at peel ph3.
  LDA_H(0, 0); STAGE_A(65536, 1, 1);
  BAR(); MFMA_Q(0, 0, b0r); BAR();
  LDB_H(b1r, 0, 1);
  BAR(); MFMA_Q(0, 1, b1r); BAR();
  LDA_H(0, 1);
  BAR(); MFMA_Q(1, 1, b1r); BAR();
  WAITVM0(); BAR(); MFMA_Q(1, 0, b0r); LDB_H(b0r, 65536, 0); BAR();
  LDA_H(65536, 0);
  BAR(); MFMA_Q(0, 0, b0r); BAR();
  LDB_H(b1r, 65536, 1);
  BAR(); MFMA_Q(0, 1, b1r); BAR();
  LDA_H(65536, 1);
  BAR(); MFMA_Q(1, 1, b1r); BAR();
  MFMA_Q(1, 0, b0r);

  // C/D layout: col = lane&15, row = kh*4 + j
  const long gm0 = (long)by * 256 + wm * 128;
  const long gn0 = (long)bx * 256 + wn * 64;
  if constexpr (EPI == 7) {
    // bias + fp32 residual -> bf16 out
    unsigned short* C = (unsigned short*)Cv + (long)bz * sC;
    const float* R = (const float*)residv + (long)bz * sR;
#pragma unroll
    for (int mg = 0; mg < 8; ++mg)
#pragma unroll
      for (int ng = 0; ng < 4; ++ng) {
        const long col = gn0 + ng * 16 + lr;
        const float bcol = bias[col];
#pragma unroll
        for (int j = 0; j < 4; ++j) {
          const long row = gm0 + mg * 16 + kh * 4 + j;
          C[row * ldc + col] = f2bf(acc[mg][ng][j] + bcol + R[row * ldr + col]);
        }
      }
  } else if constexpr (EPI == 8) {
    // bias + bf16 residual -> bf16 out
    unsigned short* C = (unsigned short*)Cv + (long)bz * sC;
    const unsigned short* R = (const unsigned short*)residv + (long)bz * sR;
#pragma unroll
    for (int mg = 0; mg < 8; ++mg)
#pragma unroll
      for (int ng = 0; ng < 4; ++ng) {
        const long col = gn0 + ng * 16 + lr;
        const float bcol = bias[col];
#pragma unroll
        for (int j = 0; j < 4; ++j) {
          const long row = gm0 + mg * 16 + kh * 4 + j;
          C[row * ldc + col] =
              f2bf(acc[mg][ng][j] + bcol + bf2f(R[row * ldr + col]));
        }
      }
  } else {
    unsigned short* C = (unsigned short*)Cv + (long)bz * sC;
    const bool do_elu = (EPI == 5) && (gn0 < 2048);  // wave-uniform segment
#pragma unroll
    for (int mg = 0; mg < 8; ++mg)
#pragma unroll
      for (int ng = 0; ng < 4; ++ng) {
        const long col = gn0 + ng * 16 + lr;
        float bcol = 0.f;
        if constexpr (EPI != 0) bcol = bias[col];
#pragma unroll
        for (int j = 0; j < 4; ++j) {
          const long row = gm0 + mg * 16 + kh * 4 + j;
          float v = acc[mg][ng][j] + bcol;
          if constexpr (EPI == 3) v = fmaxf(v, 0.f);  // relu
          if constexpr (EPI == 5) {
            if (do_elu) v = (v > 0.f) ? (v + 1.f) : expf(v);  // elu+1
          }
          C[row * ldc + col] = f2bf(v);
        }
      }
  }
#undef STAGE_A
#undef STAGE_B
#undef LDA_H
#undef LDB_H
#undef MFMA_Q
}

// ---------------------------------------------------------------------------
// transpose: in rows indexed (s*8+b) with element stride ld -> out [B][D][S].
// grid (S/64, D/64, B), 256 threads, LDS 64x68 tile.
// ---------------------------------------------------------------------------
__global__ __launch_bounds__(256) void transpose_kernel(
    const unsigned short* __restrict__ in, unsigned short* __restrict__ out,
    long ld) {
  __shared__ unsigned short t[64][68];
  const int b = blockIdx.z;
  const long s0 = (long)blockIdx.x * 64, d0 = (long)blockIdx.y * 64;
  const int tid = threadIdx.x;
  {
    const int r = tid >> 3, c = (tid & 7) * 8;
#pragma unroll
    for (int it = 0; it < 2; ++it) {
      const int s = r + it * 32;
      const unsigned short* g = &in[((s0 + s) * B_DIM + b) * ld + d0 + c];
      short4_t v0 = *(const short4_t*)g;
      short4_t v1 = *(const short4_t*)(g + 4);
      *(short4_t*)&t[s][c] = v0;
      *(short4_t*)&t[s][c + 4] = v1;
    }
  }
  __syncthreads();
  {
    const int d = tid >> 3, c = (tid & 7) * 8;
#pragma unroll
    for (int it = 0; it < 2; ++it) {
      const int dd = d + it * 32;
      short8 v;
#pragma unroll
      for (int j = 0; j < 8; ++j) v[j] = (short)t[c + j][dd];
      *(short8*)&out[(long)b * ((long)D_DIM * S_DIM) + (d0 + dd) * S_DIM + s0 + c] = v;
    }
  }
}

// ---------------------------------------------------------------------------
// layernorm bf16-in over last dim (1024). OUT_FP32: fp32 out, else bf16 out.
// ---------------------------------------------------------------------------
template <int OUT_FP32>
__global__ __launch_bounds__(256) void layernorm_bf_kernel(
    const unsigned short* __restrict__ in, void* __restrict__ outv,
    const float* __restrict__ gamma, const float* __restrict__ beta) {
  const long row = blockIdx.x;
  const int tid = threadIdx.x;
  const int lane = tid & 63, w = tid >> 6;
  short4_t r4 = *(const short4_t*)&in[row * D_DIM + tid * 4];
  f32x4 v;
#pragma unroll
  for (int j = 0; j < 4; ++j) v[j] = bf2f((unsigned short)r4[j]);
  float s = v[0] + v[1] + v[2] + v[3];
  float q = v[0] * v[0] + v[1] * v[1] + v[2] * v[2] + v[3] * v[3];
#pragma unroll
  for (int off = 32; off > 0; off >>= 1) {
    s += __shfl_down(s, off, 64);
    q += __shfl_down(q, off, 64);
  }
  __shared__ float red[8];
  if (lane == 0) { red[w] = s; red[w + 4] = q; }
  __syncthreads();
  s = red[0] + red[1] + red[2] + red[3];
  q = red[4] + red[5] + red[6] + red[7];
  const float mu = s * (1.f / D_DIM);
  const float var = q * (1.f / D_DIM) - mu * mu;
  const float rs = rsqrtf(var + 1e-5f);
  f32x4 g = *(const f32x4*)&gamma[tid * 4];
  f32x4 bb = *(const f32x4*)&beta[tid * 4];
  if constexpr (OUT_FP32) {
    f32x4 o;
#pragma unroll
    for (int j = 0; j < 4; ++j) o[j] = (v[j] - mu) * rs * g[j] + bb[j];
    *(f32x4*)&((float*)outv)[row * D_DIM + tid * 4] = o;
  } else {
    short4_t ob;
#pragma unroll
    for (int j = 0; j < 4; ++j)
      ob[j] = (short)f2bf((v[j] - mu) * rs * g[j] + bb[j]);
    *(short4_t*)&((unsigned short*)outv)[row * D_DIM + tid * 4] = ob;
  }
}

__global__ __launch_bounds__(256) void cast_kernel(
    const float* __restrict__ in, unsigned short* __restrict__ out, long n) {
  long i = ((long)blockIdx.x * 256 + threadIdx.x) * 8;
  if (i >= n) return;
  f32x4 a = *(const f32x4*)&in[i];
  f32x4 b = *(const f32x4*)&in[i + 4];
  short8 v;
#pragma unroll
  for (int j = 0; j < 4; ++j) v[j] = (short)f2bf(a[j]);
#pragma unroll
  for (int j = 0; j < 4; ++j) v[4 + j] = (short)f2bf(b[j]);
  *(short8*)&out[i] = v;
}

// ---------------------------------------------------------------------------
// Workspace plan (MB offsets; 240 MB peak). Timeline-checked:
//   0-8 w1b, 8-16 w2b (persist)
//   16-48  srcb (dead@QKV) -> Kt (dead@KV) -> AOb bf16 (dead@LN1)
//          -> Yb bf16 (FFN2 out, read@LN2)
//   48-80  Vt (dead@KV) -> Xb bf16 (read@FFN1 A, @FFN2 resid)
//   80-96  KVm (dead@Mt) | 96-112 Mt (dead@AO)
//   112-240 wqkvb(112-118)+bqkv(118-119)+wob(119-121) dead@Mt;
//           QKVb(144-240, dead@AO) -> H(112-240, written@FFN1)
// ---------------------------------------------------------------------------
extern "C" void kernel_launch(void* const* d_in, const int* in_sizes, int n_in,
                              void* d_out, int out_size, void* d_ws, size_t ws_size,
                              hipStream_t stream) {
  const float* src = (const float*)d_in[0];
  const float* wq  = (const float*)d_in[1];
  const float* bq  = (const float*)d_in[2];
  const float* wk  = (const float*)d_in[3];
  const float* bk  = (const float*)d_in[4];
  const float* wv  = (const float*)d_in[5];
  const float* bv  = (const float*)d_in[6];
  const float* wo  = (const float*)d_in[7];
  const float* bo  = (const float*)d_in[8];
  const float* w1  = (const float*)d_in[9];
  const float* b1  = (const float*)d_in[10];
  const float* w2  = (const float*)d_in[11];
  const float* b2  = (const float*)d_in[12];
  const float* g1  = (const float*)d_in[13];
  const float* be1 = (const float*)d_in[14];
  const float* g2  = (const float*)d_in[15];
  const float* be2 = (const float*)d_in[16];

  const long MB = 1024L * 1024L;
  if (ws_size < 248 * MB) return;
  char* ws = (char*)d_ws;
  unsigned short* w1b   = (unsigned short*)(ws + 0 * MB);
  unsigned short* w2b   = (unsigned short*)(ws + 8 * MB);
  unsigned short* srcb  = (unsigned short*)(ws + 16 * MB);
  unsigned short* Kt    = (unsigned short*)(ws + 16 * MB);   // after srcb dead
  unsigned short* AOb   = (unsigned short*)(ws + 16 * MB);   // after Kt dead
  unsigned short* Yb    = (unsigned short*)(ws + 16 * MB);   // after AOb dead
  unsigned short* Vt    = (unsigned short*)(ws + 48 * MB);
  unsigned short* Xb    = (unsigned short*)(ws + 48 * MB);   // after Vt dead
  unsigned short* KVm   = (unsigned short*)(ws + 80 * MB);
  unsigned short* Mt    = (unsigned short*)(ws + 96 * MB);
  unsigned short* wqkvb = (unsigned short*)(ws + 112 * MB);  // 6 MB
  float*          bqkv  = (float*)(ws + 118 * MB);           // 12 KB
  unsigned short* wob   = (unsigned short*)(ws + 119 * MB);  // 2 MB
  unsigned short* QKVb  = (unsigned short*)(ws + 144 * MB);  // 96 MB
  unsigned short* H     = (unsigned short*)(ws + 112 * MB);  // after QKV dead

  const dim3 blk(256);
  const dim3 blk512(512);
  // casts + packed bias
  cast_kernel<<<dim3(512), blk, 0, stream>>>(wq, wqkvb, 1048576);
  cast_kernel<<<dim3(512), blk, 0, stream>>>(wk, wqkvb + 1048576, 1048576);
  cast_kernel<<<dim3(512), blk, 0, stream>>>(wv, wqkvb + 2097152, 1048576);
  cast_kernel<<<dim3(512), blk, 0, stream>>>(wo, wob, 1048576);
  cast_kernel<<<dim3(2048), blk, 0, stream>>>(w1, w1b, 4194304);
  cast_kernel<<<dim3(2048), blk, 0, stream>>>(w2, w2b, 4194304);
  cast_kernel<<<dim3(8192), blk, 0, stream>>>(src, srcb, 16777216);
  hipMemcpyAsync(bqkv, bq, 4096, hipMemcpyDeviceToDevice, stream);
  hipMemcpyAsync(bqkv + 1024, bk, 4096, hipMemcpyDeviceToDevice, stream);
  hipMemcpyAsync(bqkv + 2048, bv, 4096, hipMemcpyDeviceToDevice, stream);

  // fused QKV: [16384,1024] @ [3072,1024]^T -> QKVb [16384,3072]
  gemm256_kernel<5><<<dim3(12, 64, 1), blk512, 0, stream>>>(
      srcb, 1024, 0, wqkvb, 1024, 0, QKVb, 3072, 0, bqkv, nullptr, 0, 0, 1024);

  // per-batch transposes of K,V slices -> [B][D][S]
  transpose_kernel<<<dim3(32, 16, 8), blk, 0, stream>>>(QKVb + 1024, Kt, 3072);
  transpose_kernel<<<dim3(32, 16, 8), blk, 0, stream>>>(QKVb + 2048, Vt, 3072);

  // KV[d,f] = sum_s Kt[d,s]*Vt[f,s]  (M=N=1024, K=2048, batch 8)
  gemm256_kernel<0><<<dim3(4, 4, 8), blk512, 0, stream>>>(
      Kt, 2048, 2097152, Vt, 2048, 2097152, KVm, 1024, 1048576,
      nullptr, nullptr, 0, 0, 2048);
  // Mt[e,d] = sum_f wo[e,f]*KV[d,f]  (M=N=1024, K=1024, batch 8)
  gemm256_kernel<0><<<dim3(4, 4, 8), blk512, 0, stream>>>(
      wob, 1024, 0, KVm, 1024, 1048576, Mt, 1024, 1048576,
      nullptr, nullptr, 0, 0, 1024);
  // AO[s,b,e] = sum_d Q[s,b,d]*Mt[e,d] + bo[e] + src -> bf16 AOb
  gemm256_kernel<7><<<dim3(4, 8, 8), blk512, 0, stream>>>(
      QKVb, 24576, 3072, Mt, 1024, 1048576, AOb, 8192, 1024,
      bo, src, 8192, 1024, 1024);

  // x = LN(AOb) -> Xb bf16
  layernorm_bf_kernel<0><<<dim3(16384), blk, 0, stream>>>(AOb, Xb, g1, be1);

  // FFN, full M=16384
  gemm256_kernel<3><<<dim3(16, 64, 1), blk512, 0, stream>>>(
      Xb, 1024, 0, w1b, 1024, 0, H, 4096, 0, b1, nullptr, 0, 0, 1024);
  gemm256_kernel<8><<<dim3(4, 64, 1), blk512, 0, stream>>>(
      H, 4096, 0, w2b, 4096, 0, Yb, 1024, 0, b2, Xb, 1024, 0, 4096);

  // final LN: bf16 Yb -> fp32 d_out
  layernorm_bf_kernel<1><<<dim3(16384), blk, 0, stream>>>(
      Yb, (float*)d_out, g2, be2);
}

// Round 12
// 589.533 us; speedup vs baseline: 1.1186x; 1.0343x over previous
//
#include <hip/hip_runtime.h>
#include <hip/hip_bf16.h>
#include <math.h>

// ---------------------------------------------------------------------------
// CustomTransformerEncoderLayer (linear attention, ELU+1 feature map)
// S=2048 B=8 D=1024 F=4096, fp32 in/out, bf16 MFMA internals.
//
// Round 12: launch-count consolidation (GEMM kernel byte-identical to the
// passing R11 -- five schedule variants all measured 41-42% MfmaUtil, axis
// closed). 7 casts -> 1 segmented kernel; 3 bias memcpys -> 1 kernel;
// 2 transposes -> 1 launch (z selects K/V slice). Graph nodes 20 -> 11;
// attacks the ~80us of inter-dispatch overhead in the ledger.
// ---------------------------------------------------------------------------

typedef __attribute__((ext_vector_type(8))) short short8;
typedef __attribute__((ext_vector_type(4))) short short4_t;
typedef __attribute__((ext_vector_type(4))) float f32x4;

#define S_DIM 2048
#define B_DIM 8
#define D_DIM 1024
#define F_DIM 4096

__device__ __forceinline__ unsigned short f2bf(float f) {
  __hip_bfloat16 h = __float2bfloat16(f);
  return *reinterpret_cast<unsigned short*>(&h);
}
__device__ __forceinline__ float bf2f(unsigned short u) {
  return __bfloat162float(*reinterpret_cast<const __hip_bfloat16*>(&u));
}

#define GLD16(gp, sp)                                              \
  __builtin_amdgcn_global_load_lds(                                \
      (const __attribute__((address_space(1))) void*)(gp),         \
      (__attribute__((address_space(3))) void*)(sp), 16, 0, 0)

#define BAR()                                  \
  do {                                         \
    asm volatile("" ::: "memory");             \
    __builtin_amdgcn_s_barrier();              \
    asm volatile("" ::: "memory");             \
  } while (0)
#define WAITVM6() asm volatile("s_waitcnt vmcnt(6)" ::: "memory")
#define WAITVM10() asm volatile("s_waitcnt vmcnt(10)" ::: "memory")
#define WAITVM0() asm volatile("s_waitcnt vmcnt(0)" ::: "memory")

// ---------------------------------------------------------------------------
// gemm256: C[i,j] = sum_k A[i,k]*B[j,k], BM=BN=256, BK=64, 512 thr (8 waves
// 2Mx4N), per-wave 128x64 output. 8-phase K-loop, double-buffered 128KiB LDS,
// chunk^row XOR swizzle (0 bank conflicts), vmcnt(6) at ph3/ph7 only.
// Requires M%256==0, N%256==0, K%128==0, K>=256, gridDim.x*gridDim.y%8==0.
// LDS map: buf b at b*65536 B; A_h at h*16384, B_nh at 32768+nh*16384.
// Region slot(row r, chunk c') holds global chunk c = c' ^ (r&7) (16B chunks).
// Schedule identical to R9/R11 (see R9 audit).
// EPI: 0 ->bf16 (no bias), 3 relu+bias->bf16, 5 bias+(col<2048?elu)->bf16,
//      7 bias+fp32resid->bf16, 8 bias+bf16resid->bf16
// ---------------------------------------------------------------------------
template <int EPI>
__global__ __launch_bounds__(512, 2) void gemm256_kernel(
    const unsigned short* __restrict__ A, long lda, long sA,
    const unsigned short* __restrict__ B, long ldb, long sB,
    void* __restrict__ Cv, long ldc, long sC,
    const float* __restrict__ bias,
    const void* __restrict__ residv, long ldr, long sR, int K) {
  __shared__ short lds[65536];  // 128 KiB
  // T1 XCD swizzle
  const int gx = gridDim.x;
  const int nwg = gx * gridDim.y;
  const int orig = blockIdx.y * gx + blockIdx.x;
  const int cpx = nwg >> 3;
  const int wgid = (orig & 7) * cpx + (orig >> 3);
  const int bx = wgid % gx, by = wgid / gx;
  const int bz = blockIdx.z;
  const unsigned short* Ablk = A + (long)bz * sA + (long)by * 256 * lda;
  const unsigned short* Bblk = B + (long)bz * sB + (long)bx * 256 * ldb;

  const int tid = threadIdx.x;
  const int w = tid >> 6, lane = tid & 63;
  const int wm = w >> 2, wn = w & 3;
  const int lr = lane & 15, kh = lane >> 4;

  // staging geometry (2 global_load_lds per thread per quarter-region)
  const int sr = w * 8 + (lane >> 3);              // l=0 local row (0..63)
  const int sc = ((lane & 7) ^ (lane >> 3)) * 8;   // inverse-swizzled src col
  const int br0 = sr + ((sr >> 5) << 5);
  const unsigned short* pA = Ablk + (long)sr * lda + sc;   // A h=0, load0
  const unsigned short* pB = Bblk + (long)br0 * ldb + sc;  // B nh=0, load0
  const long dA1 = 128 * lda, dAh = 64 * lda;
  const long dB1 = 128 * ldb, dBh = 32 * ldb;
  const int dst0 = w * 1024;
  const int dst1 = (8 + w) * 1024;

#define STAGE_A(bufOff, h, rel)                                               \
  do {                                                                        \
    GLD16(pA + (h) * dAh + (rel) * 64,                                        \
          (char*)lds + (bufOff) + (h)*16384 + dst0);                          \
    GLD16(pA + (h) * dAh + dA1 + (rel) * 64,                                  \
          (char*)lds + (bufOff) + (h)*16384 + dst1);                          \
  } while (0)
#define STAGE_B(bufOff, nh, rel)                                              \
  do {                                                                        \
    GLD16(pB + (nh) * dBh + (rel) * 64,                                       \
          (char*)lds + (bufOff) + 32768 + (nh)*16384 + dst0);                 \
    GLD16(pB + (nh) * dBh + dB1 + (rel) * 64,                                 \
          (char*)lds + (bufOff) + 32768 + (nh)*16384 + dst1);                 \
  } while (0)

  // fragment-read geometry
  const int chk0 = ((kh ^ (lr & 7)) << 4);
  const int chk1 = (((4 + kh) ^ (lr & 7)) << 4);
  const int aRdBase = (wm * 64 + lr) * 128;
  const int bRdBase = (wn * 32 + lr) * 128;

  short8 af[4][2], b0r[2][2], b1r[2][2];
  f32x4 acc[8][4];
#pragma unroll
  for (int m = 0; m < 8; ++m)
#pragma unroll
    for (int n = 0; n < 4; ++n)
#pragma unroll
      for (int j = 0; j < 4; ++j) acc[m][n][j] = 0.f;

#define LDA_H(bufOff, h)                                                     \
  do {                                                                       \
    const char* _p = (const char*)lds + (bufOff) + (h)*16384 + aRdBase;      \
    _Pragma("unroll") for (int m = 0; m < 4; ++m) {                          \
      af[m][0] = *(const short8*)(_p + m * 2048 + chk0);                     \
      af[m][1] = *(const short8*)(_p + m * 2048 + chk1);                     \
    }                                                                        \
  } while (0)
#define LDB_H(dst, bufOff, nh)                                               \
  do {                                                                       \
    const char* _p = (const char*)lds + (bufOff) + 32768 + (nh)*16384 + bRdBase; \
    _Pragma("unroll") for (int n = 0; n < 2; ++n) {                          \
      dst[n][0] = *(const short8*)(_p + n * 2048 + chk0);                    \
      dst[n][1] = *(const short8*)(_p + n * 2048 + chk1);                    \
    }                                                                        \
  } while (0)
// ks-outer: consecutive MFMAs hit distinct acc registers (dep distance 8).
#define MFMA_Q(mh, nh, bset)                                                 \
  do {                                                                       \
    __builtin_amdgcn_s_setprio(1);                                           \
    _Pragma("unroll") for (int ks = 0; ks < 2; ++ks)                         \
    _Pragma("unroll") for (int m = 0; m < 4; ++m)                            \
    _Pragma("unroll") for (int n = 0; n < 2; ++n)                            \
      acc[(mh)*4 + m][(nh)*2 + n] = __builtin_amdgcn_mfma_f32_16x16x32_bf16( \
          af[m][ks], bset[n][ks], acc[(mh)*4 + m][(nh)*2 + n], 0, 0, 0);     \
    __builtin_amdgcn_s_setprio(0);                                           \
  } while (0)

  const int T = K >> 6;  // T even, >=4
  // prologue FIFO: t0.{A0,B0,B1,A1} -> buf0, t1.{A0,B0,B1} -> buf1.
  STAGE_A(0, 0, 0); STAGE_B(0, 0, 0); STAGE_B(0, 1, 0); STAGE_A(0, 1, 0);
  STAGE_A(65536, 0, 1); STAGE_B(65536, 0, 1); STAGE_B(65536, 1, 1);
  WAITVM10(); BAR();
  LDB_H(b0r, 0, 0);  // preload even-tile B0

  for (int i = 0; i < (T >> 1) - 1; ++i) {
    // ph0
    LDA_H(0, 0); STAGE_A(65536, 1, 1);
    BAR(); MFMA_Q(0, 0, b0r); BAR();
    // ph1
    LDB_H(b1r, 0, 1); STAGE_A(0, 0, 2);
    BAR(); MFMA_Q(0, 1, b1r); BAR();
    // ph2
    LDA_H(0, 1); STAGE_B(0, 0, 2);
    BAR(); MFMA_Q(1, 1, b1r); BAR();
    // ph3: vmcnt(6) lands the odd tile; post-MFMA read of b1.B0.
    STAGE_B(0, 1, 2);
    WAITVM6(); BAR(); MFMA_Q(1, 0, b0r); LDB_H(b0r, 65536, 0); BAR();
    // ph4
    LDA_H(65536, 0); STAGE_A(0, 1, 2);
    BAR(); MFMA_Q(0, 0, b0r); BAR();
    // ph5
    LDB_H(b1r, 65536, 1); STAGE_A(65536, 0, 3);
    BAR(); MFMA_Q(0, 1, b1r); BAR();
    // ph6
    LDA_H(65536, 1); STAGE_B(65536, 0, 3);
    BAR(); MFMA_Q(1, 1, b1r); BAR();
    // ph7: vmcnt(6) lands the next even tile; read b0.B0(rel2) post-MFMA.
    STAGE_B(65536, 1, 3);
    WAITVM6(); BAR(); MFMA_Q(1, 0, b0r); LDB_H(b0r, 0, 0); BAR();
    pA += 128; pB += 128;  // advance 2 K-tiles
  }

  // ---- peeled last iteration: tiles T-2 (buf0, rel0) and T-1 (buf1, rel1).
  // ph0 stages the one missing quarter (T-1's A1); vmcnt(0) at peel ph3.
  LDA_H(0, 0); STAGE_A(65536, 1, 1);
  BAR(); MFMA_Q(0, 0, b0r); BAR();
  LDB_H(b1r, 0, 1);
  BAR(); MFMA_Q(0, 1, b1r); BAR();
  LDA_H(0, 1);
  BAR(); MFMA_Q(1, 1, b1r); BAR();
  WAITVM0(); BAR(); MFMA_Q(1, 0, b0r); LDB_H(b0r, 65536, 0); BAR();
  LDA_H(65536, 0);
  BAR(); MFMA_Q(0, 0, b0r); BAR();
  LDB_H(b1r, 65536, 1);
  BAR(); MFMA_Q(0, 1, b1r); BAR();
  LDA_H(65536, 1);
  BAR(); MFMA_Q(1, 1, b1r); BAR();
  MFMA_Q(1, 0, b0r);

  // C/D layout: col = lane&15, row = kh*4 + j
  const long gm0 = (long)by * 256 + wm * 128;
  const long gn0 = (long)bx * 256 + wn * 64;
  if constexpr (EPI == 7) {
    // bias + fp32 residual -> bf16 out
    unsigned short* C = (unsigned short*)Cv + (long)bz * sC;
    const float* R = (const float*)residv + (long)bz * sR;
#pragma unroll
    for (int mg = 0; mg < 8; ++mg)
#pragma unroll
      for (int ng = 0; ng < 4; ++ng) {
        const long col = gn0 + ng * 16 + lr;
        const float bcol = bias[col];
#pragma unroll
        for (int j = 0; j < 4; ++j) {
          const long row = gm0 + mg * 16 + kh * 4 + j;
          C[row * ldc + col] = f2bf(acc[mg][ng][j] + bcol + R[row * ldr + col]);
        }
      }
  } else if constexpr (EPI == 8) {
    // bias + bf16 residual -> bf16 out
    unsigned short* C = (unsigned short*)Cv + (long)bz * sC;
    const unsigned short* R = (const unsigned short*)residv + (long)bz * sR;
#pragma unroll
    for (int mg = 0; mg < 8; ++mg)
#pragma unroll
      for (int ng = 0; ng < 4; ++ng) {
        const long col = gn0 + ng * 16 + lr;
        const float bcol = bias[col];
#pragma unroll
        for (int j = 0; j < 4; ++j) {
          const long row = gm0 + mg * 16 + kh * 4 + j;
          C[row * ldc + col] =
              f2bf(acc[mg][ng][j] + bcol + bf2f(R[row * ldr + col]));
        }
      }
  } else {
    unsigned short* C = (unsigned short*)Cv + (long)bz * sC;
    const bool do_elu = (EPI == 5) && (gn0 < 2048);  // wave-uniform segment
#pragma unroll
    for (int mg = 0; mg < 8; ++mg)
#pragma unroll
      for (int ng = 0; ng < 4; ++ng) {
        const long col = gn0 + ng * 16 + lr;
        float bcol = 0.f;
        if constexpr (EPI != 0) bcol = bias[col];
#pragma unroll
        for (int j = 0; j < 4; ++j) {
          const long row = gm0 + mg * 16 + kh * 4 + j;
          float v = acc[mg][ng][j] + bcol;
          if constexpr (EPI == 3) v = fmaxf(v, 0.f);  // relu
          if constexpr (EPI == 5) {
            if (do_elu) v = (v > 0.f) ? (v + 1.f) : expf(v);  // elu+1
          }
          C[row * ldc + col] = f2bf(v);
        }
      }
  }
#undef STAGE_A
#undef STAGE_B
#undef LDA_H
#undef LDB_H
#undef MFMA_Q
}

// ---------------------------------------------------------------------------
// merged transpose: z in [0,16): which = z>>3 selects K (0) / V (1) slice of
// QKVb; b = z&7 is the batch. out = Kt + which*16MB-shorts (Kt,Vt contiguous).
// grid (S/64, D/64, 16), 256 threads, LDS 64x68 tile.
// ---------------------------------------------------------------------------
__global__ __launch_bounds__(256) void transpose_kernel(
    const unsigned short* __restrict__ inbase,
    unsigned short* __restrict__ outbase, long ld) {
  __shared__ unsigned short t[64][68];
  const int z = blockIdx.z;
  const int which = z >> 3, b = z & 7;
  const unsigned short* in = inbase + (which ? 2048 : 1024);
  unsigned short* out = outbase + (long)which * 16777216L;
  const long s0 = (long)blockIdx.x * 64, d0 = (long)blockIdx.y * 64;
  const int tid = threadIdx.x;
  {
    const int r = tid >> 3, c = (tid & 7) * 8;
#pragma unroll
    for (int it = 0; it < 2; ++it) {
      const int s = r + it * 32;
      const unsigned short* g = &in[((s0 + s) * B_DIM + b) * ld + d0 + c];
      short4_t v0 = *(const short4_t*)g;
      short4_t v1 = *(const short4_t*)(g + 4);
      *(short4_t*)&t[s][c] = v0;
      *(short4_t*)&t[s][c + 4] = v1;
    }
  }
  __syncthreads();
  {
    const int d = tid >> 3, c = (tid & 7) * 8;
#pragma unroll
    for (int it = 0; it < 2; ++it) {
      const int dd = d + it * 32;
      short8 v;
#pragma unroll
      for (int j = 0; j < 8; ++j) v[j] = (short)t[c + j][dd];
      *(short8*)&out[(long)b * ((long)D_DIM * S_DIM) + (d0 + dd) * S_DIM + s0 + c] = v;
    }
  }
}

// ---------------------------------------------------------------------------
// layernorm bf16-in over last dim (1024). OUT_FP32: fp32 out, else bf16 out.
// ---------------------------------------------------------------------------
template <int OUT_FP32>
__global__ __launch_bounds__(256) void layernorm_bf_kernel(
    const unsigned short* __restrict__ in, void* __restrict__ outv,
    const float* __restrict__ gamma, const float* __restrict__ beta) {
  const long row = blockIdx.x;
  const int tid = threadIdx.x;
  const int lane = tid & 63, w = tid >> 6;
  short4_t r4 = *(const short4_t*)&in[row * D_DIM + tid * 4];
  f32x4 v;
#pragma unroll
  for (int j = 0; j < 4; ++j) v[j] = bf2f((unsigned short)r4[j]);
  float s = v[0] + v[1] + v[2] + v[3];
  float q = v[0] * v[0] + v[1] * v[1] + v[2] * v[2] + v[3] * v[3];
#pragma unroll
  for (int off = 32; off > 0; off >>= 1) {
    s += __shfl_down(s, off, 64);
    q += __shfl_down(q, off, 64);
  }
  __shared__ float red[8];
  if (lane == 0) { red[w] = s; red[w + 4] = q; }
  __syncthreads();
  s = red[0] + red[1] + red[2] + red[3];
  q = red[4] + red[5] + red[6] + red[7];
  const float mu = s * (1.f / D_DIM);
  const float var = q * (1.f / D_DIM) - mu * mu;
  const float rs = rsqrtf(var + 1e-5f);
  f32x4 g = *(const f32x4*)&gamma[tid * 4];
  f32x4 bb = *(const f32x4*)&beta[tid * 4];
  if constexpr (OUT_FP32) {
    f32x4 o;
#pragma unroll
    for (int j = 0; j < 4; ++j) o[j] = (v[j] - mu) * rs * g[j] + bb[j];
    *(f32x4*)&((float*)outv)[row * D_DIM + tid * 4] = o;
  } else {
    short4_t ob;
#pragma unroll
    for (int j = 0; j < 4; ++j)
      ob[j] = (short)f2bf((v[j] - mu) * rs * g[j] + bb[j]);
    *(short4_t*)&((unsigned short*)outv)[row * D_DIM + tid * 4] = ob;
  }
}

// ---------------------------------------------------------------------------
// merged cast: 7 fp32->bf16 segments in one launch. Segment block ranges
// (256 thr x 8 elems = 2048 elems/block): wq/wk/wv/wo 512 blocks each,
// w1/w2 2048 each, src 8192. Grid = 14336. All sizes divide exactly.
// ---------------------------------------------------------------------------
__global__ __launch_bounds__(256) void cast_all_kernel(
    const float* __restrict__ wq, const float* __restrict__ wk,
    const float* __restrict__ wv, const float* __restrict__ wo,
    const float* __restrict__ w1, const float* __restrict__ w2,
    const float* __restrict__ src,
    unsigned short* __restrict__ wqkvb, unsigned short* __restrict__ wob,
    unsigned short* __restrict__ w1b, unsigned short* __restrict__ w2b,
    unsigned short* __restrict__ srcb) {
  int b = blockIdx.x;
  const float* in;
  unsigned short* out;
  if (b < 512)        { in = wq;  out = wqkvb;           }
  else if (b < 1024)  { in = wk;  out = wqkvb + 1048576; b -= 512;  }
  else if (b < 1536)  { in = wv;  out = wqkvb + 2097152; b -= 1024; }
  else if (b < 2048)  { in = wo;  out = wob;             b -= 1536; }
  else if (b < 4096)  { in = w1;  out = w1b;             b -= 2048; }
  else if (b < 6144)  { in = w2;  out = w2b;             b -= 4096; }
  else                { in = src; out = srcb;            b -= 6144; }
  const long i = ((long)b * 256 + threadIdx.x) * 8;
  f32x4 a = *(const f32x4*)&in[i];
  f32x4 c = *(const f32x4*)&in[i + 4];
  short8 v;
#pragma unroll
  for (int j = 0; j < 4; ++j) v[j] = (short)f2bf(a[j]);
#pragma unroll
  for (int j = 0; j < 4; ++j) v[4 + j] = (short)f2bf(c[j]);
  *(short8*)&out[i] = v;
}

// pack bq|bk|bv into bqkv (fp32). <<<3, 1024>>>.
__global__ __launch_bounds__(1024) void copy3_kernel(
    const float* __restrict__ bq, const float* __restrict__ bk,
    const float* __restrict__ bv, float* __restrict__ bqkv) {
  const float* s = blockIdx.x == 0 ? bq : (blockIdx.x == 1 ? bk : bv);
  bqkv[blockIdx.x * 1024 + threadIdx.x] = s[threadIdx.x];
}

// ---------------------------------------------------------------------------
// Workspace plan (MB offsets; 240 MB peak). Timeline-checked (same as R11):
//   0-8 w1b, 8-16 w2b (persist)
//   16-48  srcb (dead@QKV) -> Kt (dead@KV) -> AOb bf16 (dead@LN1)
//          -> Yb bf16 (FFN2 out, read@LN2)
//   48-80  Vt (dead@KV) -> Xb bf16 (read@FFN1 A, @FFN2 resid)
//   80-96  KVm (dead@Mt) | 96-112 Mt (dead@AO)
//   112-240 wqkvb(112-118)+bqkv(118-119)+wob(119-121) dead@Mt;
//           QKVb(144-240, dead@AO) -> H(112-240, written@FFN1)
// ---------------------------------------------------------------------------
extern "C" void kernel_launch(void* const* d_in, const int* in_sizes, int n_in,
                              void* d_out, int out_size, void* d_ws, size_t ws_size,
                              hipStream_t stream) {
  const float* src = (const float*)d_in[0];
  const float* wq  = (const float*)d_in[1];
  const float* bq  = (const float*)d_in[2];
  const float* wk  = (const float*)d_in[3];
  const float* bk  = (const float*)d_in[4];
  const float* wv  = (const float*)d_in[5];
  const float* bv  = (const float*)d_in[6];
  const float* wo  = (const float*)d_in[7];
  const float* bo  = (const float*)d_in[8];
  const float* w1  = (const float*)d_in[9];
  const float* b1  = (const float*)d_in[10];
  const float* w2  = (const float*)d_in[11];
  const float* b2  = (const float*)d_in[12];
  const float* g1  = (const float*)d_in[13];
  const float* be1 = (const float*)d_in[14];
  const float* g2  = (const float*)d_in[15];
  const float* be2 = (const float*)d_in[16];

  const long MB = 1024L * 1024L;
  if (ws_size < 248 * MB) return;
  char* ws = (char*)d_ws;
  unsigned short* w1b   = (unsigned short*)(ws + 0 * MB);
  unsigned short* w2b   = (unsigned short*)(ws + 8 * MB);
  unsigned short* srcb  = (unsigned short*)(ws + 16 * MB);
  unsigned short* Kt    = (unsigned short*)(ws + 16 * MB);   // after srcb dead
  unsigned short* AOb   = (unsigned short*)(ws + 16 * MB);   // after Kt dead
  unsigned short* Yb    = (unsigned short*)(ws + 16 * MB);   // after AOb dead
  unsigned short* Xb    = (unsigned short*)(ws + 48 * MB);   // after Vt dead
  unsigned short* KVm   = (unsigned short*)(ws + 80 * MB);
  unsigned short* Mt    = (unsigned short*)(ws + 96 * MB);
  unsigned short* wqkvb = (unsigned short*)(ws + 112 * MB);  // 6 MB
  float*          bqkv  = (float*)(ws + 118 * MB);           // 12 KB
  unsigned short* wob   = (unsigned short*)(ws + 119 * MB);  // 2 MB
  unsigned short* QKVb  = (unsigned short*)(ws + 144 * MB);  // 96 MB
  unsigned short* H     = (unsigned short*)(ws + 112 * MB);  // after QKV dead

  const dim3 blk(256);
  const dim3 blk512(512);
  // all casts in one launch + bias pack in one launch
  cast_all_kernel<<<dim3(14336), blk, 0, stream>>>(
      wq, wk, wv, wo, w1, w2, src, wqkvb, wob, w1b, w2b, srcb);
  copy3_kernel<<<dim3(3), dim3(1024), 0, stream>>>(bq, bk, bv, bqkv);

  // fused QKV: [16384,1024] @ [3072,1024]^T -> QKVb [16384,3072]
  gemm256_kernel<5><<<dim3(12, 64, 1), blk512, 0, stream>>>(
      srcb, 1024, 0, wqkvb, 1024, 0, QKVb, 3072, 0, bqkv, nullptr, 0, 0, 1024);

  // per-batch transposes of K,V slices -> [B][D][S], one launch (z=16)
  transpose_kernel<<<dim3(32, 16, 16), blk, 0, stream>>>(QKVb, Kt, 3072);

  // KV[d,f] = sum_s Kt[d,s]*Vt[f,s]  (M=N=1024, K=2048, batch 8)
  gemm256_kernel<0><<<dim3(4, 4, 8), blk512, 0, stream>>>(
      Kt, 2048, 2097152, Kt + 16777216L, 2048, 2097152, KVm, 1024, 1048576,
      nullptr, nullptr, 0, 0, 2048);
  // Mt[e,d] = sum_f wo[e,f]*KV[d,f]  (M=N=1024, K=1024, batch 8)
  gemm256_kernel<0><<<dim3(4, 4, 8), blk512, 0, stream>>>(
      wob, 1024, 0, KVm, 1024, 1048576, Mt, 1024, 1048576,
      nullptr, nullptr, 0, 0, 1024);
  // AO[s,b,e] = sum_d Q[s,b,d]*Mt[e,d] + bo[e] + src -> bf16 AOb
  gemm256_kernel<7><<<dim3(4, 8, 8), blk512, 0, stream>>>(
      QKVb, 24576, 3072, Mt, 1024, 1048576, AOb, 8192, 1024,
      bo, src, 8192, 1024, 1024);

  // x = LN(AOb) -> Xb bf16
  layernorm_bf_kernel<0><<<dim3(16384), blk, 0, stream>>>(AOb, Xb, g1, be1);

  // FFN, full M=16384
  gemm256_kernel<3><<<dim3(16, 64, 1), blk512, 0, stream>>>(
      Xb, 1024, 0, w1b, 1024, 0, H, 4096, 0, b1, nullptr, 0, 0, 1024);
  gemm256_kernel<8><<<dim3(4, 64, 1), blk512, 0, stream>>>(
      H, 4096, 0, w2b, 4096, 0, Yb, 1024, 0, b2, Xb, 1024, 0, 4096);

  // final LN: bf16 Yb -> fp32 d_out
  layernorm_bf_kernel<1><<<dim3(16384), blk, 0, stream>>>(
      Yb, (float*)d_out, g2, be2);
}